// Round 10
// baseline (7334.666 us; speedup 1.0000x reference)
//
#include <hip/hip_runtime.h>
#include <hip/hip_bf16.h>

// ---------- types ----------
typedef __attribute__((ext_vector_type(8))) short  s16x8;
typedef __attribute__((ext_vector_type(4))) float  f32x4;
typedef __attribute__((ext_vector_type(4))) unsigned short u16x4;
typedef __attribute__((ext_vector_type(4))) unsigned int   u32x4;

#define B_  64
#define T_  1024
#define I_  512
#define H_  1024
#define O_  512
#define MT_ 65536   // B_*T_

// scan decomposition: 8 row-groups (8 rows) x 16 col-slices (64 cols) = 128 blocks
// rg = blockIdx & 7  => under round-robin block->XCD mapping, a whole row-group
// shares ONE XCD's L2; all h exchange is then L2-local.
#define RG_   8
#define CS_   16

// ---------- helpers ----------
__device__ __forceinline__ unsigned short f2bf(float f) {
    unsigned u = __builtin_bit_cast(unsigned, f);
    u += 0x7FFFu + ((u >> 16) & 1u);
    return (unsigned short)(u >> 16);
}
__device__ __forceinline__ float bf2f(unsigned short h) {
    return __builtin_bit_cast(float, ((unsigned)h) << 16);
}
__device__ __forceinline__ void store_out(float* p, float v) { *p = v; }
__device__ __forceinline__ void store_out(unsigned short* p, float v) { *p = f2bf(v); }
__device__ __forceinline__ float to_f32(float v) { return v; }
__device__ __forceinline__ float to_f32(unsigned short v) { return bf2f(v); }

template<typename T> struct pre4;
template<> struct pre4<float>          { using t = f32x4; };
template<> struct pre4<unsigned short> { using t = u16x4; };

// async pre loads (plain cached), pinned in issue order by asm volatile
__device__ __forceinline__ f32x4 pre_ld(const float* p) {
    f32x4 d; asm volatile("global_load_dwordx4 %0, %1, off" : "=v"(d) : "v"(p)); return d;
}
__device__ __forceinline__ u16x4 pre_ld(const unsigned short* p) {
    u16x4 d; asm volatile("global_load_dwordx2 %0, %1, off" : "=v"(d) : "v"(p)); return d;
}

#define GL2LDS16(gp, lp) __builtin_amdgcn_global_load_lds( \
    (const __attribute__((address_space(1))) void*)(gp),   \
    (__attribute__((address_space(3))) void*)(lp), 16, 0, 0)

// ---------- conversion kernels ----------
__global__ void cvt_x(const float* __restrict__ src, unsigned short* __restrict__ dst, int n) {
    int stride = gridDim.x * blockDim.x * 4;
    for (int i = (blockIdx.x * blockDim.x + threadIdx.x) * 4; i < n; i += stride) {
        const float4 v = *(const float4*)(src + i);
        u16x4 o;
        o.x = f2bf(v.x); o.y = f2bf(v.y); o.z = f2bf(v.z); o.w = f2bf(v.w);
        *(u16x4*)(dst + i) = o;
    }
}

// dst[c][r] = bf16(src[row_off + r][c]);  src region [SR,SC] row-major -> dst [SC,SR]
__global__ void cvt_t(const float* __restrict__ src, unsigned short* __restrict__ dst,
                      int SR, int SC, int row_off) {
    __shared__ unsigned short tile[32][33];
    int c0 = blockIdx.x * 32, r0 = blockIdx.y * 32;
    int tx = threadIdx.x, ty = threadIdx.y;
    #pragma unroll
    for (int i = 0; i < 32; i += 8)
        tile[ty + i][tx] = f2bf(src[(size_t)(row_off + r0 + ty + i) * SC + c0 + tx]);
    __syncthreads();
    #pragma unroll
    for (int i = 0; i < 32; i += 8)
        dst[(size_t)(c0 + ty + i) * SR + r0 + tx] = tile[tx][ty + i];
}

// strip tags from final h (slot 0): dst bf16 = src u32 >> 16. Mirror (sc1) copy
// at the coherence point is always fresh.
__global__ void strip_h(const unsigned* __restrict__ src, unsigned short* __restrict__ dst) {
    int i = blockIdx.x * blockDim.x + threadIdx.x;   // 16384 uint4s
    const unsigned* p = src + i * 4;
    u32x4 v;
    asm volatile("global_load_dwordx4 %0, %1, off sc0 sc1" : "=v"(v) : "v"(p) : "memory");
    asm volatile("s_waitcnt vmcnt(0)" ::: "memory");
    u16x4 o;
    o.x = (unsigned short)(v.x >> 16); o.y = (unsigned short)(v.y >> 16);
    o.z = (unsigned short)(v.z >> 16); o.w = (unsigned short)(v.w >> 16);
    *(u16x4*)(dst + i * 4) = o;
}

// ---------- generic bf16 MFMA GEMM: C[M,N] = act(A[M,K] @ BT[N,K]^T + bias) ----------
template<typename OutT, bool LRELU, bool SCATTER>
__global__ __launch_bounds__(256)
void gemm_bf16(const unsigned short* __restrict__ A,
               const unsigned short* __restrict__ BT,
               const float* __restrict__ bias,
               OutT* __restrict__ C, int M, int K, int N)
{
    __shared__ unsigned short As[4096]; // [128][32]
    __shared__ unsigned short Bs[4096]; // [128][32]
    const int tid = threadIdx.x, lane = tid & 63, wid = tid >> 6;
    const int wr = wid >> 1, wc = wid & 1;
    const int m0 = blockIdx.x * 128, n0 = blockIdx.y * 128;

    f32x4 acc[4][4] = {};

    const int c = wid * 2;
    const int srow = lane >> 2;
    const int scol = (lane & 3) * 8;
    const unsigned short* Ag0 = A  + (size_t)(m0 + c * 16 + srow) * K + scol;
    const unsigned short* Ag1 = A  + (size_t)(m0 + c * 16 + 16 + srow) * K + scol;
    const unsigned short* Bg0 = BT + (size_t)(n0 + c * 16 + srow) * K + scol;
    const unsigned short* Bg1 = BT + (size_t)(n0 + c * 16 + 16 + srow) * K + scol;

    for (int k0 = 0; k0 < K; k0 += 32) {
        __syncthreads();
        GL2LDS16(Ag0 + k0, As + c * 512);
        GL2LDS16(Ag1 + k0, As + (c + 1) * 512);
        GL2LDS16(Bg0 + k0, Bs + c * 512);
        GL2LDS16(Bg1 + k0, Bs + (c + 1) * 512);
        __syncthreads();

        s16x8 af[4], bfr[4];
        #pragma unroll
        for (int i = 0; i < 4; i++)
            af[i] = *(const s16x8*)(As + (wr * 64 + i * 16 + (lane & 15)) * 32 + (lane >> 4) * 8);
        #pragma unroll
        for (int j = 0; j < 4; j++)
            bfr[j] = *(const s16x8*)(Bs + (wc * 64 + j * 16 + (lane & 15)) * 32 + (lane >> 4) * 8);
        #pragma unroll
        for (int i = 0; i < 4; i++)
            #pragma unroll
            for (int j = 0; j < 4; j++)
                acc[i][j] = __builtin_amdgcn_mfma_f32_16x16x32_bf16(af[i], bfr[j], acc[i][j], 0, 0, 0);
    }

    #pragma unroll
    for (int j = 0; j < 4; j++) {
        const int n = n0 + wc * 64 + j * 16 + (lane & 15);
        const float bv = bias[n];
        #pragma unroll
        for (int i = 0; i < 4; i++) {
            #pragma unroll
            for (int r = 0; r < 4; r++) {
                const int m = m0 + wr * 64 + i * 16 + (lane >> 4) * 4 + r;
                if (m < M) {
                    float v = acc[i][j][r] + bv;
                    if (LRELU) v = v >= 0.f ? v : 0.01f * v;
                    size_t row = SCATTER ? (size_t)((m & (T_ - 1)) * B_ + (m >> 10)) : (size_t)m;
                    store_out(&C[row * N + n], v);
                }
            }
        }
    }
}

// ---------- scan v10: XCD-local tagged exchange with guaranteed L3 fallback ----
// 128 blocks (8 rg x 16 cs) x 256 thr. Tagged u32 ping-pong (r9 protocol).
// Producer DUAL-STORES each piece: sc0 (cached -> shared local L2) + sc0 sc1
// (write-through mirror at L3). Consumer polls sc0 (L2-local fast path when
// co-located); a bounded watchdog (48 stale rounds) permanently switches the
// wave to sc0 sc1 mirror polling (= proven r9). Tags validate either copy, so
// placement NEVER affects correctness — only speed.

#define TAGLD(d, OFFSTR, SC) asm volatile( \
    "global_load_dwordx4 %0, %1, off offset:" OFFSTR " " SC \
    : "=v"(d) : "v"(tbase))

#define POLL16(SC) do { \
    TAGLD(tv[0],  "0",  SC); TAGLD(tv[1],  "16", SC); TAGLD(tv[2],  "128",SC); TAGLD(tv[3],  "144",SC); \
    TAGLD(tv[4],  "256",SC); TAGLD(tv[5],  "272",SC); TAGLD(tv[6],  "384",SC); TAGLD(tv[7],  "400",SC); \
    TAGLD(tv[8],  "512",SC); TAGLD(tv[9],  "528",SC); TAGLD(tv[10], "640",SC); TAGLD(tv[11], "656",SC); \
    TAGLD(tv[12], "768",SC); TAGLD(tv[13], "784",SC); TAGLD(tv[14], "896",SC); TAGLD(tv[15], "912",SC); \
    } while (0)

#define STEP(S, PVUSE, PVFILL) do { \
    const char* hc32 = (const char*)hbuf32 + (((S) & 1) << 18); \
    char*       hn32 = (char*)hbuf32 + ((((S) + 1) & 1) << 18); \
    const unsigned tagS = (unsigned)(S); \
    const char* tbase = hc32 + hrow * 4096 + w * 1024 + l4 * 32; \
    u32x4 tv[16]; \
    int tries = 0; \
    for (;;) { \
        if (fb) { POLL16("sc0 sc1"); } else { POLL16("sc0"); } \
        asm volatile("s_waitcnt vmcnt(0)" ::: "memory"); \
        __builtin_amdgcn_sched_barrier(0); \
        unsigned d_ = 0; \
        _Pragma("unroll") \
        for (int i = 0; i < 16; i++) \
            d_ |= (tv[i].x ^ tagS) | (tv[i].y ^ tagS) | (tv[i].z ^ tagS) | (tv[i].w ^ tagS); \
        if (__all((int)((d_ & 0xFFFFu) == 0u))) break; \
        if (++tries >= 48) fb = 1u; \
    } \
    { const int sn = ((S) + 1 < T_) ? (S) + 1 : (S); \
      PVFILL = pre_ld(pre + ((size_t)sn * B_ + hrow) * H_ + col0); } \
    f32x4 ac[4] = {}; \
    _Pragma("unroll") \
    for (int cg = 0; cg < 4; ++cg) { \
        const char* pE = wE + cg * 32768; \
        const char* pO = wO + cg * 32768; \
        _Pragma("unroll") \
        for (int j = 0; j < 8; ++j) { \
            u32x4 a_ = tv[2 * j], b_ = tv[2 * j + 1]; \
            u32x4 f_; \
            f_.x = (a_.x >> 16) | (a_.y & 0xFFFF0000u); \
            f_.y = (a_.z >> 16) | (a_.w & 0xFFFF0000u); \
            f_.z = (b_.x >> 16) | (b_.y & 0xFFFF0000u); \
            f_.w = (b_.z >> 16) | (b_.w & 0xFFFF0000u); \
            s16x8 hfrag = __builtin_bit_cast(s16x8, f_); \
            s16x8 g = *(const s16x8*)(((j & 1) ? pO : pE) + j * 64); \
            ac[cg] = __builtin_amdgcn_mfma_f32_16x16x32_bf16(g, hfrag, ac[cg], 0, 0, 0); \
        } \
    } \
    if (l15 < 8) { \
        float* pw_ = pbuf + (w * 8 + l15) * 68 + l4 * 4; \
        *(f32x4*)(pw_ +  0) = ac[0]; \
        *(f32x4*)(pw_ + 16) = ac[1]; \
        *(f32x4*)(pw_ + 32) = ac[2]; \
        *(f32x4*)(pw_ + 48) = ac[3]; \
    } \
    asm volatile("s_waitcnt lgkmcnt(0)" ::: "memory"); \
    __builtin_amdgcn_s_barrier(); \
    asm volatile("" ::: "memory"); \
    if (l15 < 8) { \
        const float* pr_ = pbuf + l15 * 68 + w * 16 + l4 * 4; \
        f32x4 s0 = *(const f32x4*)(pr_); \
        f32x4 s1 = *(const f32x4*)(pr_ + 544); \
        f32x4 s2 = *(const f32x4*)(pr_ + 1088); \
        f32x4 s3 = *(const f32x4*)(pr_ + 1632); \
        f32x4 sm = (s0 + s1) + (s2 + s3); \
        u32x4 ow; \
        _Pragma("unroll") \
        for (int r = 0; r < 4; r++) { \
            float v = sm[r] + to_f32(PVUSE[r]); \
            v = v >= 0.f ? v : 0.01f * v; \
            ow[r] = ((unsigned)f2bf(v) << 16) | (tagS + 1u); \
        } \
        char* sp = hn32 + hrow * 4096 + col0 * 4; \
        asm volatile("global_store_dwordx4 %0, %1, off sc0" \
                     :: "v"(sp), "v"(ow) : "memory"); \
        asm volatile("global_store_dwordx4 %0, %1, off sc0 sc1" \
                     :: "v"(sp), "v"(ow) : "memory"); \
    } \
    asm volatile("s_barrier" ::: "memory"); \
  } while (0)

template<typename PreT>
__global__ __launch_bounds__(256, 1)
void rnn_scan10(const unsigned short* __restrict__ WbotT,
                const PreT* __restrict__ pre,      // [T][B][H] t-major
                unsigned* __restrict__ hbuf32)     // [2][B][H] tagged u32
{
    using p4_t = typename pre4<PreT>::t;
    __shared__ unsigned short Ws[64 * 1024];      // 128KiB, XOR-swizzled rows
    __shared__ float pbuf[4 * 8 * 68];            // 8.7KB padded partial buffer
    const int tid = threadIdx.x, lane = tid & 63, w = tid >> 6;
    const int rg = (int)blockIdx.x & 7;           // & 7 -> same rg = same XCD (round-robin)
    const int cs = (int)blockIdx.x >> 3;
    const int row0 = rg * 8, n0 = cs * 64;

    // fill Ws swizzled: byte(r,kb) = r*2048 + (kb ^ ((r&7)<<4))
    for (int idx = tid; idx < 64 * 128; idx += 256) {
        int r = idx >> 7, kb = (idx & 127) * 16;
        s16x8 v = *(const s16x8*)(WbotT + (size_t)(n0 + r) * H_ + (idx & 127) * 8);
        *(s16x8*)((char*)Ws + r * 2048 + (kb ^ ((r & 7) << 4))) = v;
    }
    __syncthreads();

    const int l15 = lane & 15, l4 = lane >> 4;
    const int hrow = row0 + (l15 & 7);        // 8 rows; lanes l15>=8 duplicate
    const int col0 = n0 + w * 16 + l4 * 4;    // 4 consecutive output cols (reduce phase)

    // swizzled Ws read bases (weights = A operand; unchanged from r9)
    const int b6 = (l15 >> 2) & 1;
    const char* wsRow = (const char*)Ws + l15 * 2048 + ((l4 * 16) ^ ((l15 & 3) << 4)) + w * 512;
    const char* wE = wsRow + b6 * 64;   // even j
    const char* wO = wsRow - b6 * 64;   // odd j

    unsigned fb = 0;                    // sticky: 0 = L2-local poll, 1 = L3 mirror poll
    p4_t pvA, pvB;
    pvA = pre_ld(pre + (size_t)hrow * H_ + col0);   // pre[t=0]
    asm volatile("s_waitcnt vmcnt(0)" ::: "memory");

    for (int t = 0; t < T_; t += 2) {
        STEP(t,     pvA, pvB);
        STEP(t + 1, pvB, pvA);
    }
}

// ---------- launch ----------
extern "C" void kernel_launch(void* const* d_in, const int* in_sizes, int n_in,
                              void* d_out, int out_size, void* d_ws, size_t ws_size,
                              hipStream_t stream)
{
    const float* x     = (const float*)d_in[0];
    const float* W_in  = (const float*)d_in[1];
    const float* b_in  = (const float*)d_in[2];
    const float* W_h   = (const float*)d_in[3];
    const float* b_h   = (const float*)d_in[4];
    const float* W_out = (const float*)d_in[5];
    const float* b_out = (const float*)d_in[6];
    float* out = (float*)d_out;

    char* ws = (char*)d_ws;
    size_t off = 0;
    auto alloc = [&](size_t bytes) { void* p = ws + off; off += (bytes + 255) & ~(size_t)255; return p; };

    unsigned short* Xb    = (unsigned short*)alloc((size_t)MT_ * I_ * 2);
    unsigned short* WinT  = (unsigned short*)alloc((size_t)H_ * I_ * 2);
    unsigned short* WtopT = (unsigned short*)alloc((size_t)H_ * H_ * 2);
    unsigned short* WbotT = (unsigned short*)alloc((size_t)H_ * H_ * 2);
    unsigned short* WoutT = (unsigned short*)alloc((size_t)O_ * H_ * 2);
    unsigned short* Abuf  = (unsigned short*)alloc((size_t)MT_ * H_ * 2);
    unsigned*       hbuf32 = (unsigned*)alloc((size_t)2 * B_ * H_ * 4);   // tagged ping-pong
    unsigned short* hfin  = (unsigned short*)alloc((size_t)B_ * H_ * 2);  // stripped h_T
    void* pre = ws + off;
    const bool pre_f32 = (off + (size_t)MT_ * H_ * 4) <= ws_size;

    // memset 0: slot0 tag0 == step-0 tag (h0 = 0) ✓; slot1 tag0 != odd tags ✓
    hipMemsetAsync(hbuf32, 0, (size_t)2 * B_ * H_ * 4, stream);

    cvt_x<<<2048, 256, 0, stream>>>(x, Xb, MT_ * I_);
    dim3 tb(32, 8);
    cvt_t<<<dim3(H_ / 32, I_ / 32), tb, 0, stream>>>(W_in,  WinT,  I_, H_, 0);
    cvt_t<<<dim3(H_ / 32, H_ / 32), tb, 0, stream>>>(W_h,   WtopT, H_, H_, 0);
    cvt_t<<<dim3(H_ / 32, H_ / 32), tb, 0, stream>>>(W_h,   WbotT, H_, H_, H_);
    cvt_t<<<dim3(O_ / 32, H_ / 32), tb, 0, stream>>>(W_out, WoutT, H_, O_, 0);

    // GEMM1: A = lrelu(X @ W_in + b_in)   [MT, H] bf16
    gemm_bf16<unsigned short, true, false>
        <<<dim3(MT_ / 128, H_ / 128), 256, 0, stream>>>(Xb, WinT, b_in, Abuf, MT_, I_, H_);

    // GEMM2: pre = A @ Wtop + b_h   written t-major [T][B][H]
    if (pre_f32) {
        gemm_bf16<float, false, true>
            <<<dim3(MT_ / 128, H_ / 128), 256, 0, stream>>>(Abuf, WtopT, b_h, (float*)pre, MT_, H_, H_);
        rnn_scan10<float><<<RG_ * CS_, 256, 0, stream>>>(WbotT, (const float*)pre, hbuf32);
    } else {
        gemm_bf16<unsigned short, false, true>
            <<<dim3(MT_ / 128, H_ / 128), 256, 0, stream>>>(Abuf, WtopT, b_h, (unsigned short*)pre, MT_, H_, H_);
        rnn_scan10<unsigned short><<<RG_ * CS_, 256, 0, stream>>>(WbotT, (const unsigned short*)pre, hbuf32);
    }

    // h_T lives in slot 0 (tag 1024); strip tags then final GEMM
    strip_h<<<64, 256, 0, stream>>>(hbuf32, hfin);
    gemm_bf16<float, false, false>
        <<<dim3(1, O_ / 128), 256, 0, stream>>>(hfin, WoutT, b_out, out, B_, H_, O_);
}

// Round 11
// 4918.104 us; speedup vs baseline: 1.4914x; 1.4914x over previous
//
#include <hip/hip_runtime.h>
#include <hip/hip_bf16.h>

// ---------- types ----------
typedef __attribute__((ext_vector_type(8))) short  s16x8;
typedef __attribute__((ext_vector_type(4))) float  f32x4;
typedef __attribute__((ext_vector_type(4))) unsigned short u16x4;
typedef __attribute__((ext_vector_type(4))) unsigned int   u32x4;

#define B_  64
#define T_  1024
#define I_  512
#define H_  1024
#define O_  512
#define MT_ 65536   // B_*T_

// scan decomposition: 4 row-groups x 16 col-slices; 4 waves split K (r9 layout)
#define RG_   4
#define CS_   16

// ---------- helpers ----------
__device__ __forceinline__ unsigned short f2bf(float f) {
    unsigned u = __builtin_bit_cast(unsigned, f);
    u += 0x7FFFu + ((u >> 16) & 1u);
    return (unsigned short)(u >> 16);
}
__device__ __forceinline__ float bf2f(unsigned short h) {
    return __builtin_bit_cast(float, ((unsigned)h) << 16);
}
__device__ __forceinline__ void store_out(float* p, float v) { *p = v; }
__device__ __forceinline__ void store_out(unsigned short* p, float v) { *p = f2bf(v); }
__device__ __forceinline__ float to_f32(float v) { return v; }
__device__ __forceinline__ float to_f32(unsigned short v) { return bf2f(v); }

template<typename T> struct pre4;
template<> struct pre4<float>          { using t = f32x4; };
template<> struct pre4<unsigned short> { using t = u16x4; };

// async pre loads (plain cached), pinned in issue order by asm volatile
__device__ __forceinline__ f32x4 pre_ld(const float* p) {
    f32x4 d; asm volatile("global_load_dwordx4 %0, %1, off" : "=v"(d) : "v"(p)); return d;
}
__device__ __forceinline__ u16x4 pre_ld(const unsigned short* p) {
    u16x4 d; asm volatile("global_load_dwordx2 %0, %1, off" : "=v"(d) : "v"(p)); return d;
}

#define GL2LDS16(gp, lp) __builtin_amdgcn_global_load_lds( \
    (const __attribute__((address_space(1))) void*)(gp),   \
    (__attribute__((address_space(3))) void*)(lp), 16, 0, 0)

// ---------- conversion kernels ----------
__global__ void cvt_x(const float* __restrict__ src, unsigned short* __restrict__ dst, int n) {
    int stride = gridDim.x * blockDim.x * 4;
    for (int i = (blockIdx.x * blockDim.x + threadIdx.x) * 4; i < n; i += stride) {
        const float4 v = *(const float4*)(src + i);
        u16x4 o;
        o.x = f2bf(v.x); o.y = f2bf(v.y); o.z = f2bf(v.z); o.w = f2bf(v.w);
        *(u16x4*)(dst + i) = o;
    }
}

// dst[c][r] = bf16(src[row_off + r][c]);  src region [SR,SC] row-major -> dst [SC,SR]
__global__ void cvt_t(const float* __restrict__ src, unsigned short* __restrict__ dst,
                      int SR, int SC, int row_off) {
    __shared__ unsigned short tile[32][33];
    int c0 = blockIdx.x * 32, r0 = blockIdx.y * 32;
    int tx = threadIdx.x, ty = threadIdx.y;
    #pragma unroll
    for (int i = 0; i < 32; i += 8)
        tile[ty + i][tx] = f2bf(src[(size_t)(row_off + r0 + ty + i) * SC + c0 + tx]);
    __syncthreads();
    #pragma unroll
    for (int i = 0; i < 32; i += 8)
        dst[(size_t)(c0 + ty + i) * SR + r0 + tx] = tile[tx][ty + i];
}

// strip tags from final h (slot 0): dst bf16 = src u32 >> 16.
__global__ void strip_h(const unsigned* __restrict__ src, unsigned short* __restrict__ dst) {
    int i = blockIdx.x * blockDim.x + threadIdx.x;   // 16384 uint4s
    const unsigned* p = src + i * 4;
    u32x4 v;
    asm volatile("global_load_dwordx4 %0, %1, off sc0 sc1" : "=v"(v) : "v"(p) : "memory");
    asm volatile("s_waitcnt vmcnt(0)" ::: "memory");
    u16x4 o;
    o.x = (unsigned short)(v.x >> 16); o.y = (unsigned short)(v.y >> 16);
    o.z = (unsigned short)(v.z >> 16); o.w = (unsigned short)(v.w >> 16);
    *(u16x4*)(dst + i * 4) = o;
}

// ---------- generic bf16 MFMA GEMM: C[M,N] = act(A[M,K] @ BT[N,K]^T + bias) ----------
template<typename OutT, bool LRELU, bool SCATTER>
__global__ __launch_bounds__(256)
void gemm_bf16(const unsigned short* __restrict__ A,
               const unsigned short* __restrict__ BT,
               const float* __restrict__ bias,
               OutT* __restrict__ C, int M, int K, int N)
{
    __shared__ unsigned short As[4096]; // [128][32]
    __shared__ unsigned short Bs[4096]; // [128][32]
    const int tid = threadIdx.x, lane = tid & 63, wid = tid >> 6;
    const int wr = wid >> 1, wc = wid & 1;
    const int m0 = blockIdx.x * 128, n0 = blockIdx.y * 128;

    f32x4 acc[4][4] = {};

    const int c = wid * 2;
    const int srow = lane >> 2;
    const int scol = (lane & 3) * 8;
    const unsigned short* Ag0 = A  + (size_t)(m0 + c * 16 + srow) * K + scol;
    const unsigned short* Ag1 = A  + (size_t)(m0 + c * 16 + 16 + srow) * K + scol;
    const unsigned short* Bg0 = BT + (size_t)(n0 + c * 16 + srow) * K + scol;
    const unsigned short* Bg1 = BT + (size_t)(n0 + c * 16 + 16 + srow) * K + scol;

    for (int k0 = 0; k0 < K; k0 += 32) {
        __syncthreads();
        GL2LDS16(Ag0 + k0, As + c * 512);
        GL2LDS16(Ag1 + k0, As + (c + 1) * 512);
        GL2LDS16(Bg0 + k0, Bs + c * 512);
        GL2LDS16(Bg1 + k0, Bs + (c + 1) * 512);
        __syncthreads();

        s16x8 af[4], bfr[4];
        #pragma unroll
        for (int i = 0; i < 4; i++)
            af[i] = *(const s16x8*)(As + (wr * 64 + i * 16 + (lane & 15)) * 32 + (lane >> 4) * 8);
        #pragma unroll
        for (int j = 0; j < 4; j++)
            bfr[j] = *(const s16x8*)(Bs + (wc * 64 + j * 16 + (lane & 15)) * 32 + (lane >> 4) * 8);
        #pragma unroll
        for (int i = 0; i < 4; i++)
            #pragma unroll
            for (int j = 0; j < 4; j++)
                acc[i][j] = __builtin_amdgcn_mfma_f32_16x16x32_bf16(af[i], bfr[j], acc[i][j], 0, 0, 0);
    }

    #pragma unroll
    for (int j = 0; j < 4; j++) {
        const int n = n0 + wc * 64 + j * 16 + (lane & 15);
        const float bv = bias[n];
        #pragma unroll
        for (int i = 0; i < 4; i++) {
            #pragma unroll
            for (int r = 0; r < 4; r++) {
                const int m = m0 + wr * 64 + i * 16 + (lane >> 4) * 4 + r;
                if (m < M) {
                    float v = acc[i][j][r] + bv;
                    if (LRELU) v = v >= 0.f ? v : 0.01f * v;
                    size_t row = SCATTER ? (size_t)((m & (T_ - 1)) * B_ + (m >> 10)) : (size_t)m;
                    store_out(&C[row * N + n], v);
                }
            }
        }
    }
}

// ---------- scan v11: r9 tagged-data protocol + per-lane SELECTIVE retry ----------
// 64 blocks (4 rg x 16 cs) x 256 thr. h as u32 = (bf16<<16)|step_tag, ping-pong.
// Producer: fire tagged dwordx4 (sc0 sc1), no ack. Consumer: full burst once;
// then ONLY stale lanes (exec-masked divergence) re-load their 16 chunks —
// fresh lanes keep registers. Cuts retry flood ~10x, draining the L3 queue
// that inflates every round trip.

#define TAGLD(d, OFFSTR) asm volatile( \
    "global_load_dwordx4 %0, %1, off offset:" OFFSTR " sc0 sc1" \
    : "=v"(d) : "v"(tbase))

#define POLL16 do { \
    TAGLD(tv[0],  "0");   TAGLD(tv[1],  "16");  TAGLD(tv[2],  "128"); TAGLD(tv[3],  "144"); \
    TAGLD(tv[4],  "256"); TAGLD(tv[5],  "272"); TAGLD(tv[6],  "384"); TAGLD(tv[7],  "400"); \
    TAGLD(tv[8],  "512"); TAGLD(tv[9],  "528"); TAGLD(tv[10], "640"); TAGLD(tv[11], "656"); \
    TAGLD(tv[12], "768"); TAGLD(tv[13], "784"); TAGLD(tv[14], "896"); TAGLD(tv[15], "912"); \
    } while (0)

#define STEP(S, PVUSE, PVFILL) do { \
    const char* hc32 = (const char*)hbuf32 + (((S) & 1) << 18); \
    char*       hn32 = (char*)hbuf32 + ((((S) + 1) & 1) << 18); \
    const unsigned tagS = (unsigned)(S); \
    const char* tbase = hc32 + hrow * 4096 + w * 1024 + l4 * 32; \
    u32x4 tv[16]; \
    unsigned ok = 0u; \
    for (;;) { \
        if (!ok) { \
            POLL16; \
            asm volatile("s_waitcnt vmcnt(0)" ::: "memory"); \
            __builtin_amdgcn_sched_barrier(0); \
            unsigned d_ = 0; \
            _Pragma("unroll") \
            for (int i = 0; i < 16; i++) \
                d_ |= (tv[i].x ^ tagS) | (tv[i].y ^ tagS) | (tv[i].z ^ tagS) | (tv[i].w ^ tagS); \
            ok = ((d_ & 0xFFFFu) == 0u) ? 1u : 0u; \
        } \
        if (__all((int)ok)) break; \
    } \
    { const int sn = ((S) + 1 < T_) ? (S) + 1 : (S); \
      PVFILL = pre_ld(pre + ((size_t)sn * B_ + hrow) * H_ + col0); } \
    f32x4 ac[4] = {}; \
    _Pragma("unroll") \
    for (int cg = 0; cg < 4; ++cg) { \
        const char* pE = wE + cg * 32768; \
        const char* pO = wO + cg * 32768; \
        _Pragma("unroll") \
        for (int j = 0; j < 8; ++j) { \
            u32x4 a_ = tv[2 * j], b_ = tv[2 * j + 1]; \
            u32x4 f_; \
            f_.x = (a_.x >> 16) | (a_.y & 0xFFFF0000u); \
            f_.y = (a_.z >> 16) | (a_.w & 0xFFFF0000u); \
            f_.z = (b_.x >> 16) | (b_.y & 0xFFFF0000u); \
            f_.w = (b_.z >> 16) | (b_.w & 0xFFFF0000u); \
            s16x8 hfrag = __builtin_bit_cast(s16x8, f_); \
            s16x8 g = *(const s16x8*)(((j & 1) ? pO : pE) + j * 64); \
            ac[cg] = __builtin_amdgcn_mfma_f32_16x16x32_bf16(g, hfrag, ac[cg], 0, 0, 0); \
        } \
    } \
    { float* pw_ = pbuf + (w * 16 + l15) * 68 + l4 * 4; \
      *(f32x4*)(pw_ +  0) = ac[0]; \
      *(f32x4*)(pw_ + 16) = ac[1]; \
      *(f32x4*)(pw_ + 32) = ac[2]; \
      *(f32x4*)(pw_ + 48) = ac[3]; } \
    asm volatile("s_waitcnt lgkmcnt(0)" ::: "memory"); \
    __builtin_amdgcn_s_barrier(); \
    asm volatile("" ::: "memory"); \
    { const float* pr_ = pbuf + l15 * 68 + w * 16 + l4 * 4; \
      f32x4 s0 = *(const f32x4*)(pr_); \
      f32x4 s1 = *(const f32x4*)(pr_ + 1088); \
      f32x4 s2 = *(const f32x4*)(pr_ + 2176); \
      f32x4 s3 = *(const f32x4*)(pr_ + 3264); \
      f32x4 sm = (s0 + s1) + (s2 + s3); \
      u32x4 ow; \
      _Pragma("unroll") \
      for (int r = 0; r < 4; r++) { \
          float v = sm[r] + to_f32(PVUSE[r]); \
          v = v >= 0.f ? v : 0.01f * v; \
          ow[r] = ((unsigned)f2bf(v) << 16) | (tagS + 1u); \
      } \
      char* sp = hn32 + hrow * 4096 + col0 * 4; \
      asm volatile("global_store_dwordx4 %0, %1, off sc0 sc1" \
                   :: "v"(sp), "v"(ow) : "memory"); } \
    asm volatile("s_barrier" ::: "memory"); \
  } while (0)

template<typename PreT>
__global__ __launch_bounds__(256, 1)
void rnn_scan11(const unsigned short* __restrict__ WbotT,
                const PreT* __restrict__ pre,      // [T][B][H] t-major
                unsigned* __restrict__ hbuf32)     // [2][B][H] tagged u32
{
    using p4_t = typename pre4<PreT>::t;
    __shared__ unsigned short Ws[64 * 1024];      // 128KiB, XOR-swizzled rows
    __shared__ float pbuf[4 * 16 * 68];           // 17KB padded partial buffer
    const int tid = threadIdx.x, lane = tid & 63, w = tid >> 6;
    const int rg = (int)blockIdx.x >> 4;
    const int cs = (int)blockIdx.x & 15;
    const int row0 = rg * 16, n0 = cs * 64;

    // fill Ws swizzled: byte(r,kb) = r*2048 + (kb ^ ((r&7)<<4))
    for (int idx = tid; idx < 64 * 128; idx += 256) {
        int r = idx >> 7, kb = (idx & 127) * 16;
        s16x8 v = *(const s16x8*)(WbotT + (size_t)(n0 + r) * H_ + (idx & 127) * 8);
        *(s16x8*)((char*)Ws + r * 2048 + (kb ^ ((r & 7) << 4))) = v;
    }
    __syncthreads();

    const int l15 = lane & 15, l4 = lane >> 4;
    const int hrow = row0 + l15;              // h row this thread reads AND writes
    const int col0 = n0 + w * 16 + l4 * 4;    // 4 consecutive output cols (reduce phase)

    // swizzled Ws read bases: row = cg*16+l15, kbyte = l4*16 + (8w+j)*64
    const int b6 = (l15 >> 2) & 1;
    const char* wsRow = (const char*)Ws + l15 * 2048 + ((l4 * 16) ^ ((l15 & 3) << 4)) + w * 512;
    const char* wE = wsRow + b6 * 64;   // even j
    const char* wO = wsRow - b6 * 64;   // odd j

    p4_t pvA, pvB;
    pvA = pre_ld(pre + (size_t)hrow * H_ + col0);   // pre[t=0]
    asm volatile("s_waitcnt vmcnt(0)" ::: "memory");

    for (int t = 0; t < T_; t += 2) {
        STEP(t,     pvA, pvB);
        STEP(t + 1, pvB, pvA);
    }
}

// ---------- launch ----------
extern "C" void kernel_launch(void* const* d_in, const int* in_sizes, int n_in,
                              void* d_out, int out_size, void* d_ws, size_t ws_size,
                              hipStream_t stream)
{
    const float* x     = (const float*)d_in[0];
    const float* W_in  = (const float*)d_in[1];
    const float* b_in  = (const float*)d_in[2];
    const float* W_h   = (const float*)d_in[3];
    const float* b_h   = (const float*)d_in[4];
    const float* W_out = (const float*)d_in[5];
    const float* b_out = (const float*)d_in[6];
    float* out = (float*)d_out;

    char* ws = (char*)d_ws;
    size_t off = 0;
    auto alloc = [&](size_t bytes) { void* p = ws + off; off += (bytes + 255) & ~(size_t)255; return p; };

    unsigned short* Xb    = (unsigned short*)alloc((size_t)MT_ * I_ * 2);
    unsigned short* WinT  = (unsigned short*)alloc((size_t)H_ * I_ * 2);
    unsigned short* WtopT = (unsigned short*)alloc((size_t)H_ * H_ * 2);
    unsigned short* WbotT = (unsigned short*)alloc((size_t)H_ * H_ * 2);
    unsigned short* WoutT = (unsigned short*)alloc((size_t)O_ * H_ * 2);
    unsigned short* Abuf  = (unsigned short*)alloc((size_t)MT_ * H_ * 2);
    unsigned*       hbuf32 = (unsigned*)alloc((size_t)2 * B_ * H_ * 4);   // tagged ping-pong
    unsigned short* hfin  = (unsigned short*)alloc((size_t)B_ * H_ * 2);  // stripped h_T
    void* pre = ws + off;
    const bool pre_f32 = (off + (size_t)MT_ * H_ * 4) <= ws_size;

    // memset 0: slot0 tag0 == step-0 tag (h0 = 0) ✓; slot1 tag0 != odd tags ✓
    hipMemsetAsync(hbuf32, 0, (size_t)2 * B_ * H_ * 4, stream);

    cvt_x<<<2048, 256, 0, stream>>>(x, Xb, MT_ * I_);
    dim3 tb(32, 8);
    cvt_t<<<dim3(H_ / 32, I_ / 32), tb, 0, stream>>>(W_in,  WinT,  I_, H_, 0);
    cvt_t<<<dim3(H_ / 32, H_ / 32), tb, 0, stream>>>(W_h,   WtopT, H_, H_, 0);
    cvt_t<<<dim3(H_ / 32, H_ / 32), tb, 0, stream>>>(W_h,   WbotT, H_, H_, H_);
    cvt_t<<<dim3(O_ / 32, H_ / 32), tb, 0, stream>>>(W_out, WoutT, H_, O_, 0);

    // GEMM1: A = lrelu(X @ W_in + b_in)   [MT, H] bf16
    gemm_bf16<unsigned short, true, false>
        <<<dim3(MT_ / 128, H_ / 128), 256, 0, stream>>>(Xb, WinT, b_in, Abuf, MT_, I_, H_);

    // GEMM2: pre = A @ Wtop + b_h   written t-major [T][B][H]
    if (pre_f32) {
        gemm_bf16<float, false, true>
            <<<dim3(MT_ / 128, H_ / 128), 256, 0, stream>>>(Abuf, WtopT, b_h, (float*)pre, MT_, H_, H_);
        rnn_scan11<float><<<RG_ * CS_, 256, 0, stream>>>(WbotT, (const float*)pre, hbuf32);
    } else {
        gemm_bf16<unsigned short, false, true>
            <<<dim3(MT_ / 128, H_ / 128), 256, 0, stream>>>(Abuf, WtopT, b_h, (unsigned short*)pre, MT_, H_, H_);
        rnn_scan11<unsigned short><<<RG_ * CS_, 256, 0, stream>>>(WbotT, (const unsigned short*)pre, hbuf32);
    }

    // h_T lives in slot 0 (tag 1024); strip tags then final GEMM
    strip_h<<<64, 256, 0, stream>>>(hbuf32, hfin);
    gemm_bf16<float, false, false>
        <<<dim3(1, O_ / 128), 256, 0, stream>>>(hfin, WoutT, b_out, out, B_, H_, O_);
}

// Round 12
// 4560.503 us; speedup vs baseline: 1.6083x; 1.0784x over previous
//
#include <hip/hip_runtime.h>
#include <hip/hip_bf16.h>

// ---------- types ----------
typedef __attribute__((ext_vector_type(8))) short  s16x8;
typedef __attribute__((ext_vector_type(4))) float  f32x4;
typedef __attribute__((ext_vector_type(4))) unsigned short u16x4;
typedef __attribute__((ext_vector_type(4))) unsigned int   u32x4;

#define B_  64
#define T_  1024
#define I_  512
#define H_  1024
#define O_  512
#define MT_ 65536   // B_*T_

// scan decomposition: 4 row-groups x 16 col-slices; 4 waves split K (r9 layout)
#define RG_   4
#define CS_   16

// ---------- helpers ----------
__device__ __forceinline__ unsigned short f2bf(float f) {
    unsigned u = __builtin_bit_cast(unsigned, f);
    u += 0x7FFFu + ((u >> 16) & 1u);
    return (unsigned short)(u >> 16);
}
__device__ __forceinline__ float bf2f(unsigned short h) {
    return __builtin_bit_cast(float, ((unsigned)h) << 16);
}
__device__ __forceinline__ void store_out(float* p, float v) { *p = v; }
__device__ __forceinline__ void store_out(unsigned short* p, float v) { *p = f2bf(v); }
__device__ __forceinline__ float to_f32(float v) { return v; }
__device__ __forceinline__ float to_f32(unsigned short v) { return bf2f(v); }

template<typename T> struct pre4;
template<> struct pre4<float>          { using t = f32x4; };
template<> struct pre4<unsigned short> { using t = u16x4; };

// async pre loads (plain cached), pinned in issue order by asm volatile
__device__ __forceinline__ f32x4 pre_ld(const float* p) {
    f32x4 d; asm volatile("global_load_dwordx4 %0, %1, off" : "=v"(d) : "v"(p)); return d;
}
__device__ __forceinline__ u16x4 pre_ld(const unsigned short* p) {
    u16x4 d; asm volatile("global_load_dwordx2 %0, %1, off" : "=v"(d) : "v"(p)); return d;
}

#define GL2LDS16(gp, lp) __builtin_amdgcn_global_load_lds( \
    (const __attribute__((address_space(1))) void*)(gp),   \
    (__attribute__((address_space(3))) void*)(lp), 16, 0, 0)

// ---------- conversion kernels ----------
__global__ void cvt_x(const float* __restrict__ src, unsigned short* __restrict__ dst, int n) {
    int stride = gridDim.x * blockDim.x * 4;
    for (int i = (blockIdx.x * blockDim.x + threadIdx.x) * 4; i < n; i += stride) {
        const float4 v = *(const float4*)(src + i);
        u16x4 o;
        o.x = f2bf(v.x); o.y = f2bf(v.y); o.z = f2bf(v.z); o.w = f2bf(v.w);
        *(u16x4*)(dst + i) = o;
    }
}

// dst[c][r] = bf16(src[row_off + r][c]);  src region [SR,SC] row-major -> dst [SC,SR]
__global__ void cvt_t(const float* __restrict__ src, unsigned short* __restrict__ dst,
                      int SR, int SC, int row_off) {
    __shared__ unsigned short tile[32][33];
    int c0 = blockIdx.x * 32, r0 = blockIdx.y * 32;
    int tx = threadIdx.x, ty = threadIdx.y;
    #pragma unroll
    for (int i = 0; i < 32; i += 8)
        tile[ty + i][tx] = f2bf(src[(size_t)(row_off + r0 + ty + i) * SC + c0 + tx]);
    __syncthreads();
    #pragma unroll
    for (int i = 0; i < 32; i += 8)
        dst[(size_t)(c0 + ty + i) * SR + r0 + tx] = tile[tx][ty + i];
}

// strip tags from final h (slot 0): dst bf16 = src u32 >> 16.
__global__ void strip_h(const unsigned* __restrict__ src, unsigned short* __restrict__ dst) {
    int i = blockIdx.x * blockDim.x + threadIdx.x;   // 16384 uint4s
    const unsigned* p = src + i * 4;
    u32x4 v;
    asm volatile("global_load_dwordx4 %0, %1, off sc0 sc1" : "=v"(v) : "v"(p) : "memory");
    asm volatile("s_waitcnt vmcnt(0)" ::: "memory");
    u16x4 o;
    o.x = (unsigned short)(v.x >> 16); o.y = (unsigned short)(v.y >> 16);
    o.z = (unsigned short)(v.z >> 16); o.w = (unsigned short)(v.w >> 16);
    *(u16x4*)(dst + i * 4) = o;
}

// ---------- generic bf16 MFMA GEMM: C[M,N] = act(A[M,K] @ BT[N,K]^T + bias) ----------
template<typename OutT, bool LRELU, bool SCATTER>
__global__ __launch_bounds__(256)
void gemm_bf16(const unsigned short* __restrict__ A,
               const unsigned short* __restrict__ BT,
               const float* __restrict__ bias,
               OutT* __restrict__ C, int M, int K, int N)
{
    __shared__ unsigned short As[4096]; // [128][32]
    __shared__ unsigned short Bs[4096]; // [128][32]
    const int tid = threadIdx.x, lane = tid & 63, wid = tid >> 6;
    const int wr = wid >> 1, wc = wid & 1;
    const int m0 = blockIdx.x * 128, n0 = blockIdx.y * 128;

    f32x4 acc[4][4] = {};

    const int c = wid * 2;
    const int srow = lane >> 2;
    const int scol = (lane & 3) * 8;
    const unsigned short* Ag0 = A  + (size_t)(m0 + c * 16 + srow) * K + scol;
    const unsigned short* Ag1 = A  + (size_t)(m0 + c * 16 + 16 + srow) * K + scol;
    const unsigned short* Bg0 = BT + (size_t)(n0 + c * 16 + srow) * K + scol;
    const unsigned short* Bg1 = BT + (size_t)(n0 + c * 16 + 16 + srow) * K + scol;

    for (int k0 = 0; k0 < K; k0 += 32) {
        __syncthreads();
        GL2LDS16(Ag0 + k0, As + c * 512);
        GL2LDS16(Ag1 + k0, As + (c + 1) * 512);
        GL2LDS16(Bg0 + k0, Bs + c * 512);
        GL2LDS16(Bg1 + k0, Bs + (c + 1) * 512);
        __syncthreads();

        s16x8 af[4], bfr[4];
        #pragma unroll
        for (int i = 0; i < 4; i++)
            af[i] = *(const s16x8*)(As + (wr * 64 + i * 16 + (lane & 15)) * 32 + (lane >> 4) * 8);
        #pragma unroll
        for (int j = 0; j < 4; j++)
            bfr[j] = *(const s16x8*)(Bs + (wc * 64 + j * 16 + (lane & 15)) * 32 + (lane >> 4) * 8);
        #pragma unroll
        for (int i = 0; i < 4; i++)
            #pragma unroll
            for (int j = 0; j < 4; j++)
                acc[i][j] = __builtin_amdgcn_mfma_f32_16x16x32_bf16(af[i], bfr[j], acc[i][j], 0, 0, 0);
    }

    #pragma unroll
    for (int j = 0; j < 4; j++) {
        const int n = n0 + wc * 64 + j * 16 + (lane & 15);
        const float bv = bias[n];
        #pragma unroll
        for (int i = 0; i < 4; i++) {
            #pragma unroll
            for (int r = 0; r < 4; r++) {
                const int m = m0 + wr * 64 + i * 16 + (lane >> 4) * 4 + r;
                if (m < M) {
                    float v = acc[i][j][r] + bv;
                    if (LRELU) v = v >= 0.f ? v : 0.01f * v;
                    size_t row = SCATTER ? (size_t)((m & (T_ - 1)) * B_ + (m >> 10)) : (size_t)m;
                    store_out(&C[row * N + n], v);
                }
            }
        }
    }
}

// ---------- scan v12: r11 + ADAPTIVE PRE-POLL SLEEP ----------
// Insight from r9/r11: step = 2*RT + compute because poll round 1 (issued right
// after our store) always returns STALE; round 2 (at +2*RT) is fresh. Fix: a
// per-wave self-tuning sleep before the first poll so round 1 lands fresh:
// rounds>1 -> slp += 2; rounds==1 -> slp -= 1. Pure delay; correctness intact.

#define TAGLD(d, OFFSTR) asm volatile( \
    "global_load_dwordx4 %0, %1, off offset:" OFFSTR " sc0 sc1" \
    : "=v"(d) : "v"(tbase))

#define POLL16 do { \
    TAGLD(tv[0],  "0");   TAGLD(tv[1],  "16");  TAGLD(tv[2],  "128"); TAGLD(tv[3],  "144"); \
    TAGLD(tv[4],  "256"); TAGLD(tv[5],  "272"); TAGLD(tv[6],  "384"); TAGLD(tv[7],  "400"); \
    TAGLD(tv[8],  "512"); TAGLD(tv[9],  "528"); TAGLD(tv[10], "640"); TAGLD(tv[11], "656"); \
    TAGLD(tv[12], "768"); TAGLD(tv[13], "784"); TAGLD(tv[14], "896"); TAGLD(tv[15], "912"); \
    } while (0)

#define STEP(S, PVUSE, PVFILL) do { \
    const char* hc32 = (const char*)hbuf32 + (((S) & 1) << 18); \
    char*       hn32 = (char*)hbuf32 + ((((S) + 1) & 1) << 18); \
    const unsigned tagS = (unsigned)(S); \
    const char* tbase = hc32 + hrow * 4096 + w * 1024 + l4 * 32; \
    for (int i_ = 0; i_ < slp; ++i_) __builtin_amdgcn_s_sleep(2); \
    u32x4 tv[16]; \
    unsigned ok = 0u; \
    int rounds_ = 0; \
    for (;;) { \
        if (!ok) { \
            POLL16; \
            asm volatile("s_waitcnt vmcnt(0)" ::: "memory"); \
            __builtin_amdgcn_sched_barrier(0); \
            unsigned d_ = 0; \
            _Pragma("unroll") \
            for (int i = 0; i < 16; i++) \
                d_ |= (tv[i].x ^ tagS) | (tv[i].y ^ tagS) | (tv[i].z ^ tagS) | (tv[i].w ^ tagS); \
            ok = ((d_ & 0xFFFFu) == 0u) ? 1u : 0u; \
        } \
        ++rounds_; \
        if (__all((int)ok)) break; \
    } \
    slp = (rounds_ > 1) ? (slp + 2 > 24 ? 24 : slp + 2) : (slp > 0 ? slp - 1 : 0); \
    { const int sn = ((S) + 1 < T_) ? (S) + 1 : (S); \
      PVFILL = pre_ld(pre + ((size_t)sn * B_ + hrow) * H_ + col0); } \
    f32x4 ac[4] = {}; \
    _Pragma("unroll") \
    for (int cg = 0; cg < 4; ++cg) { \
        const char* pE = wE + cg * 32768; \
        const char* pO = wO + cg * 32768; \
        _Pragma("unroll") \
        for (int j = 0; j < 8; ++j) { \
            u32x4 a_ = tv[2 * j], b_ = tv[2 * j + 1]; \
            u32x4 f_; \
            f_.x = (a_.x >> 16) | (a_.y & 0xFFFF0000u); \
            f_.y = (a_.z >> 16) | (a_.w & 0xFFFF0000u); \
            f_.z = (b_.x >> 16) | (b_.y & 0xFFFF0000u); \
            f_.w = (b_.z >> 16) | (b_.w & 0xFFFF0000u); \
            s16x8 hfrag = __builtin_bit_cast(s16x8, f_); \
            s16x8 g = *(const s16x8*)(((j & 1) ? pO : pE) + j * 64); \
            ac[cg] = __builtin_amdgcn_mfma_f32_16x16x32_bf16(g, hfrag, ac[cg], 0, 0, 0); \
        } \
    } \
    { float* pw_ = pbuf + (w * 16 + l15) * 68 + l4 * 4; \
      *(f32x4*)(pw_ +  0) = ac[0]; \
      *(f32x4*)(pw_ + 16) = ac[1]; \
      *(f32x4*)(pw_ + 32) = ac[2]; \
      *(f32x4*)(pw_ + 48) = ac[3]; } \
    asm volatile("s_waitcnt lgkmcnt(0)" ::: "memory"); \
    __builtin_amdgcn_s_barrier(); \
    asm volatile("" ::: "memory"); \
    { const float* pr_ = pbuf + l15 * 68 + w * 16 + l4 * 4; \
      f32x4 s0 = *(const f32x4*)(pr_); \
      f32x4 s1 = *(const f32x4*)(pr_ + 1088); \
      f32x4 s2 = *(const f32x4*)(pr_ + 2176); \
      f32x4 s3 = *(const f32x4*)(pr_ + 3264); \
      f32x4 sm = (s0 + s1) + (s2 + s3); \
      u32x4 ow; \
      _Pragma("unroll") \
      for (int r = 0; r < 4; r++) { \
          float v = sm[r] + to_f32(PVUSE[r]); \
          v = v >= 0.f ? v : 0.01f * v; \
          ow[r] = ((unsigned)f2bf(v) << 16) | (tagS + 1u); \
      } \
      char* sp = hn32 + hrow * 4096 + col0 * 4; \
      asm volatile("global_store_dwordx4 %0, %1, off sc0 sc1" \
                   :: "v"(sp), "v"(ow) : "memory"); } \
    asm volatile("s_barrier" ::: "memory"); \
  } while (0)

template<typename PreT>
__global__ __launch_bounds__(256, 1)
void rnn_scan12(const unsigned short* __restrict__ WbotT,
                const PreT* __restrict__ pre,      // [T][B][H] t-major
                unsigned* __restrict__ hbuf32)     // [2][B][H] tagged u32
{
    using p4_t = typename pre4<PreT>::t;
    __shared__ unsigned short Ws[64 * 1024];      // 128KiB, XOR-swizzled rows
    __shared__ float pbuf[4 * 16 * 68];           // 17KB padded partial buffer
    const int tid = threadIdx.x, lane = tid & 63, w = tid >> 6;
    const int rg = (int)blockIdx.x >> 4;
    const int cs = (int)blockIdx.x & 15;
    const int row0 = rg * 16, n0 = cs * 64;

    // fill Ws swizzled: byte(r,kb) = r*2048 + (kb ^ ((r&7)<<4))
    for (int idx = tid; idx < 64 * 128; idx += 256) {
        int r = idx >> 7, kb = (idx & 127) * 16;
        s16x8 v = *(const s16x8*)(WbotT + (size_t)(n0 + r) * H_ + (idx & 127) * 8);
        *(s16x8*)((char*)Ws + r * 2048 + (kb ^ ((r & 7) << 4))) = v;
    }
    __syncthreads();

    const int l15 = lane & 15, l4 = lane >> 4;
    const int hrow = row0 + l15;              // h row this thread reads AND writes
    const int col0 = n0 + w * 16 + l4 * 4;    // 4 consecutive output cols (reduce phase)

    // swizzled Ws read bases: row = cg*16+l15, kbyte = l4*16 + (8w+j)*64
    const int b6 = (l15 >> 2) & 1;
    const char* wsRow = (const char*)Ws + l15 * 2048 + ((l4 * 16) ^ ((l15 & 3) << 4)) + w * 512;
    const char* wE = wsRow + b6 * 64;   // even j
    const char* wO = wsRow - b6 * 64;   // odd j

    int slp = 0;                        // adaptive pre-poll sleep (per wave)
    p4_t pvA, pvB;
    pvA = pre_ld(pre + (size_t)hrow * H_ + col0);   // pre[t=0]
    asm volatile("s_waitcnt vmcnt(0)" ::: "memory");

    for (int t = 0; t < T_; t += 2) {
        STEP(t,     pvA, pvB);
        STEP(t + 1, pvB, pvA);
    }
}

// ---------- launch ----------
extern "C" void kernel_launch(void* const* d_in, const int* in_sizes, int n_in,
                              void* d_out, int out_size, void* d_ws, size_t ws_size,
                              hipStream_t stream)
{
    const float* x     = (const float*)d_in[0];
    const float* W_in  = (const float*)d_in[1];
    const float* b_in  = (const float*)d_in[2];
    const float* W_h   = (const float*)d_in[3];
    const float* b_h   = (const float*)d_in[4];
    const float* W_out = (const float*)d_in[5];
    const float* b_out = (const float*)d_in[6];
    float* out = (float*)d_out;

    char* ws = (char*)d_ws;
    size_t off = 0;
    auto alloc = [&](size_t bytes) { void* p = ws + off; off += (bytes + 255) & ~(size_t)255; return p; };

    unsigned short* Xb    = (unsigned short*)alloc((size_t)MT_ * I_ * 2);
    unsigned short* WinT  = (unsigned short*)alloc((size_t)H_ * I_ * 2);
    unsigned short* WtopT = (unsigned short*)alloc((size_t)H_ * H_ * 2);
    unsigned short* WbotT = (unsigned short*)alloc((size_t)H_ * H_ * 2);
    unsigned short* WoutT = (unsigned short*)alloc((size_t)O_ * H_ * 2);
    unsigned short* Abuf  = (unsigned short*)alloc((size_t)MT_ * H_ * 2);
    unsigned*       hbuf32 = (unsigned*)alloc((size_t)2 * B_ * H_ * 4);   // tagged ping-pong
    unsigned short* hfin  = (unsigned short*)alloc((size_t)B_ * H_ * 2);  // stripped h_T
    void* pre = ws + off;
    const bool pre_f32 = (off + (size_t)MT_ * H_ * 4) <= ws_size;

    // memset 0: slot0 tag0 == step-0 tag (h0 = 0) ✓; slot1 tag0 != odd tags ✓
    hipMemsetAsync(hbuf32, 0, (size_t)2 * B_ * H_ * 4, stream);

    cvt_x<<<2048, 256, 0, stream>>>(x, Xb, MT_ * I_);
    dim3 tb(32, 8);
    cvt_t<<<dim3(H_ / 32, I_ / 32), tb, 0, stream>>>(W_in,  WinT,  I_, H_, 0);
    cvt_t<<<dim3(H_ / 32, H_ / 32), tb, 0, stream>>>(W_h,   WtopT, H_, H_, 0);
    cvt_t<<<dim3(H_ / 32, H_ / 32), tb, 0, stream>>>(W_h,   WbotT, H_, H_, H_);
    cvt_t<<<dim3(O_ / 32, H_ / 32), tb, 0, stream>>>(W_out, WoutT, H_, O_, 0);

    // GEMM1: A = lrelu(X @ W_in + b_in)   [MT, H] bf16
    gemm_bf16<unsigned short, true, false>
        <<<dim3(MT_ / 128, H_ / 128), 256, 0, stream>>>(Xb, WinT, b_in, Abuf, MT_, I_, H_);

    // GEMM2: pre = A @ Wtop + b_h   written t-major [T][B][H]
    if (pre_f32) {
        gemm_bf16<float, false, true>
            <<<dim3(MT_ / 128, H_ / 128), 256, 0, stream>>>(Abuf, WtopT, b_h, (float*)pre, MT_, H_, H_);
        rnn_scan12<float><<<RG_ * CS_, 256, 0, stream>>>(WbotT, (const float*)pre, hbuf32);
    } else {
        gemm_bf16<unsigned short, false, true>
            <<<dim3(MT_ / 128, H_ / 128), 256, 0, stream>>>(Abuf, WtopT, b_h, (unsigned short*)pre, MT_, H_, H_);
        rnn_scan12<unsigned short><<<RG_ * CS_, 256, 0, stream>>>(WbotT, (const unsigned short*)pre, hbuf32);
    }

    // h_T lives in slot 0 (tag 1024); strip tags then final GEMM
    strip_h<<<64, 256, 0, stream>>>(hbuf32, hfin);
    gemm_bf16<float, false, false>
        <<<dim3(1, O_ / 128), 256, 0, stream>>>(hfin, WoutT, b_out, out, B_, H_, O_);
}

// Round 13
// 4407.364 us; speedup vs baseline: 1.6642x; 1.0347x over previous
//
#include <hip/hip_runtime.h>
#include <hip/hip_bf16.h>

// ---------- types ----------
typedef __attribute__((ext_vector_type(8))) short  s16x8;
typedef __attribute__((ext_vector_type(4))) float  f32x4;
typedef __attribute__((ext_vector_type(4))) unsigned short u16x4;
typedef __attribute__((ext_vector_type(4))) unsigned int   u32x4;

#define B_  64
#define T_  1024
#define I_  512
#define H_  1024
#define O_  512
#define MT_ 65536   // B_*T_

// scan decomposition: 4 row-groups x 16 col-slices; 4 waves split K (r9 layout)
#define RG_   4
#define CS_   16

// ---------- helpers ----------
__device__ __forceinline__ unsigned short f2bf(float f) {
    unsigned u = __builtin_bit_cast(unsigned, f);
    u += 0x7FFFu + ((u >> 16) & 1u);
    return (unsigned short)(u >> 16);
}
__device__ __forceinline__ float bf2f(unsigned short h) {
    return __builtin_bit_cast(float, ((unsigned)h) << 16);
}
__device__ __forceinline__ void store_out(float* p, float v) { *p = v; }
__device__ __forceinline__ void store_out(unsigned short* p, float v) { *p = f2bf(v); }
// non-temporal stores (keep streamed data out of L3 — protects hbuf residency)
__device__ __forceinline__ void store_nt(float* p, float v) {
    asm volatile("global_store_dword %0, %1, off nt" :: "v"(p), "v"(v) : "memory");
}
__device__ __forceinline__ void store_nt(unsigned short* p, float v) {
    unsigned short h = f2bf(v);
    asm volatile("global_store_short %0, %1, off nt" :: "v"(p), "v"(h) : "memory");
}
__device__ __forceinline__ float to_f32(float v) { return v; }
__device__ __forceinline__ float to_f32(unsigned short v) { return bf2f(v); }

template<typename T> struct pre4;
template<> struct pre4<float>          { using t = f32x4; };
template<> struct pre4<unsigned short> { using t = u16x4; };

// async pre loads — NON-TEMPORAL (read-once stream; do not thrash L3)
__device__ __forceinline__ f32x4 pre_ld(const float* p) {
    f32x4 d; asm volatile("global_load_dwordx4 %0, %1, off nt" : "=v"(d) : "v"(p)); return d;
}
__device__ __forceinline__ u16x4 pre_ld(const unsigned short* p) {
    u16x4 d; asm volatile("global_load_dwordx2 %0, %1, off nt" : "=v"(d) : "v"(p)); return d;
}

#define GL2LDS16(gp, lp) __builtin_amdgcn_global_load_lds( \
    (const __attribute__((address_space(1))) void*)(gp),   \
    (__attribute__((address_space(3))) void*)(lp), 16, 0, 0)

// ---------- conversion kernels ----------
__global__ void cvt_x(const float* __restrict__ src, unsigned short* __restrict__ dst, int n) {
    int stride = gridDim.x * blockDim.x * 4;
    for (int i = (blockIdx.x * blockDim.x + threadIdx.x) * 4; i < n; i += stride) {
        const float4 v = *(const float4*)(src + i);
        u16x4 o;
        o.x = f2bf(v.x); o.y = f2bf(v.y); o.z = f2bf(v.z); o.w = f2bf(v.w);
        *(u16x4*)(dst + i) = o;
    }
}

// dst[c][r] = bf16(src[row_off + r][c]);  src region [SR,SC] row-major -> dst [SC,SR]
__global__ void cvt_t(const float* __restrict__ src, unsigned short* __restrict__ dst,
                      int SR, int SC, int row_off) {
    __shared__ unsigned short tile[32][33];
    int c0 = blockIdx.x * 32, r0 = blockIdx.y * 32;
    int tx = threadIdx.x, ty = threadIdx.y;
    #pragma unroll
    for (int i = 0; i < 32; i += 8)
        tile[ty + i][tx] = f2bf(src[(size_t)(row_off + r0 + ty + i) * SC + c0 + tx]);
    __syncthreads();
    #pragma unroll
    for (int i = 0; i < 32; i += 8)
        dst[(size_t)(c0 + ty + i) * SR + r0 + tx] = tile[tx][ty + i];
}

// strip tags from final h (slot 0): dst bf16 = src u32 >> 16.
__global__ void strip_h(const unsigned* __restrict__ src, unsigned short* __restrict__ dst) {
    int i = blockIdx.x * blockDim.x + threadIdx.x;   // 16384 uint4s
    const unsigned* p = src + i * 4;
    u32x4 v;
    asm volatile("global_load_dwordx4 %0, %1, off sc0 sc1" : "=v"(v) : "v"(p) : "memory");
    asm volatile("s_waitcnt vmcnt(0)" ::: "memory");
    u16x4 o;
    o.x = (unsigned short)(v.x >> 16); o.y = (unsigned short)(v.y >> 16);
    o.z = (unsigned short)(v.z >> 16); o.w = (unsigned short)(v.w >> 16);
    *(u16x4*)(dst + i * 4) = o;
}

// ---------- generic bf16 MFMA GEMM: C[M,N] = act(A[M,K] @ BT[N,K]^T + bias) ----------
template<typename OutT, bool LRELU, bool SCATTER>
__global__ __launch_bounds__(256)
void gemm_bf16(const unsigned short* __restrict__ A,
               const unsigned short* __restrict__ BT,
               const float* __restrict__ bias,
               OutT* __restrict__ C, int M, int K, int N)
{
    __shared__ unsigned short As[4096]; // [128][32]
    __shared__ unsigned short Bs[4096]; // [128][32]
    const int tid = threadIdx.x, lane = tid & 63, wid = tid >> 6;
    const int wr = wid >> 1, wc = wid & 1;
    const int m0 = blockIdx.x * 128, n0 = blockIdx.y * 128;

    f32x4 acc[4][4] = {};

    const int c = wid * 2;
    const int srow = lane >> 2;
    const int scol = (lane & 3) * 8;
    const unsigned short* Ag0 = A  + (size_t)(m0 + c * 16 + srow) * K + scol;
    const unsigned short* Ag1 = A  + (size_t)(m0 + c * 16 + 16 + srow) * K + scol;
    const unsigned short* Bg0 = BT + (size_t)(n0 + c * 16 + srow) * K + scol;
    const unsigned short* Bg1 = BT + (size_t)(n0 + c * 16 + 16 + srow) * K + scol;

    for (int k0 = 0; k0 < K; k0 += 32) {
        __syncthreads();
        GL2LDS16(Ag0 + k0, As + c * 512);
        GL2LDS16(Ag1 + k0, As + (c + 1) * 512);
        GL2LDS16(Bg0 + k0, Bs + c * 512);
        GL2LDS16(Bg1 + k0, Bs + (c + 1) * 512);
        __syncthreads();

        s16x8 af[4], bfr[4];
        #pragma unroll
        for (int i = 0; i < 4; i++)
            af[i] = *(const s16x8*)(As + (wr * 64 + i * 16 + (lane & 15)) * 32 + (lane >> 4) * 8);
        #pragma unroll
        for (int j = 0; j < 4; j++)
            bfr[j] = *(const s16x8*)(Bs + (wc * 64 + j * 16 + (lane & 15)) * 32 + (lane >> 4) * 8);
        #pragma unroll
        for (int i = 0; i < 4; i++)
            #pragma unroll
            for (int j = 0; j < 4; j++)
                acc[i][j] = __builtin_amdgcn_mfma_f32_16x16x32_bf16(af[i], bfr[j], acc[i][j], 0, 0, 0);
    }

    #pragma unroll
    for (int j = 0; j < 4; j++) {
        const int n = n0 + wc * 64 + j * 16 + (lane & 15);
        const float bv = bias[n];
        #pragma unroll
        for (int i = 0; i < 4; i++) {
            #pragma unroll
            for (int r = 0; r < 4; r++) {
                const int m = m0 + wr * 64 + i * 16 + (lane >> 4) * 4 + r;
                if (m < M) {
                    float v = acc[i][j][r] + bv;
                    if (LRELU) v = v >= 0.f ? v : 0.01f * v;
                    if (SCATTER) {
                        // t-major pre: streamed, written once, read once -> nt
                        size_t row = (size_t)((m & (T_ - 1)) * B_ + (m >> 10));
                        store_nt(&C[row * N + n], v);
                    } else {
                        store_out(&C[(size_t)m * N + n], v);
                    }
                }
            }
        }
    }
}

// ---------- scan v13: r12 + NT pre stream (protect hbuf L3 residency) ----------
// r12 diagnosis: 0.94 GB of poll traffic hit HBM because the pre stream evicted
// hbuf32 from L3; the slowest (HBM-served) line gated every __all() round.
// v13: pre loads/stores are nt (no L3 allocation) -> hbuf32 stays L3-hot.
// Sleep retune: +4 stale / -1 fresh, cap 24.

#define TAGLD(d, OFFSTR) asm volatile( \
    "global_load_dwordx4 %0, %1, off offset:" OFFSTR " sc0 sc1" \
    : "=v"(d) : "v"(tbase))

#define POLL16 do { \
    TAGLD(tv[0],  "0");   TAGLD(tv[1],  "16");  TAGLD(tv[2],  "128"); TAGLD(tv[3],  "144"); \
    TAGLD(tv[4],  "256"); TAGLD(tv[5],  "272"); TAGLD(tv[6],  "384"); TAGLD(tv[7],  "400"); \
    TAGLD(tv[8],  "512"); TAGLD(tv[9],  "528"); TAGLD(tv[10], "640"); TAGLD(tv[11], "656"); \
    TAGLD(tv[12], "768"); TAGLD(tv[13], "784"); TAGLD(tv[14], "896"); TAGLD(tv[15], "912"); \
    } while (0)

#define STEP(S, PVUSE, PVFILL) do { \
    const char* hc32 = (const char*)hbuf32 + (((S) & 1) << 18); \
    char*       hn32 = (char*)hbuf32 + ((((S) + 1) & 1) << 18); \
    const unsigned tagS = (unsigned)(S); \
    const char* tbase = hc32 + hrow * 4096 + w * 1024 + l4 * 32; \
    for (int i_ = 0; i_ < slp; ++i_) __builtin_amdgcn_s_sleep(2); \
    u32x4 tv[16]; \
    unsigned ok = 0u; \
    int rounds_ = 0; \
    for (;;) { \
        if (!ok) { \
            POLL16; \
            asm volatile("s_waitcnt vmcnt(0)" ::: "memory"); \
            __builtin_amdgcn_sched_barrier(0); \
            unsigned d_ = 0; \
            _Pragma("unroll") \
            for (int i = 0; i < 16; i++) \
                d_ |= (tv[i].x ^ tagS) | (tv[i].y ^ tagS) | (tv[i].z ^ tagS) | (tv[i].w ^ tagS); \
            ok = ((d_ & 0xFFFFu) == 0u) ? 1u : 0u; \
        } \
        ++rounds_; \
        if (__all((int)ok)) break; \
    } \
    slp = (rounds_ > 1) ? (slp + 4 > 24 ? 24 : slp + 4) : (slp > 0 ? slp - 1 : 0); \
    { const int sn = ((S) + 1 < T_) ? (S) + 1 : (S); \
      PVFILL = pre_ld(pre + ((size_t)sn * B_ + hrow) * H_ + col0); } \
    f32x4 ac[4] = {}; \
    _Pragma("unroll") \
    for (int cg = 0; cg < 4; ++cg) { \
        const char* pE = wE + cg * 32768; \
        const char* pO = wO + cg * 32768; \
        _Pragma("unroll") \
        for (int j = 0; j < 8; ++j) { \
            u32x4 a_ = tv[2 * j], b_ = tv[2 * j + 1]; \
            u32x4 f_; \
            f_.x = (a_.x >> 16) | (a_.y & 0xFFFF0000u); \
            f_.y = (a_.z >> 16) | (a_.w & 0xFFFF0000u); \
            f_.z = (b_.x >> 16) | (b_.y & 0xFFFF0000u); \
            f_.w = (b_.z >> 16) | (b_.w & 0xFFFF0000u); \
            s16x8 hfrag = __builtin_bit_cast(s16x8, f_); \
            s16x8 g = *(const s16x8*)(((j & 1) ? pO : pE) + j * 64); \
            ac[cg] = __builtin_amdgcn_mfma_f32_16x16x32_bf16(g, hfrag, ac[cg], 0, 0, 0); \
        } \
    } \
    { float* pw_ = pbuf + (w * 16 + l15) * 68 + l4 * 4; \
      *(f32x4*)(pw_ +  0) = ac[0]; \
      *(f32x4*)(pw_ + 16) = ac[1]; \
      *(f32x4*)(pw_ + 32) = ac[2]; \
      *(f32x4*)(pw_ + 48) = ac[3]; } \
    asm volatile("s_waitcnt lgkmcnt(0)" ::: "memory"); \
    __builtin_amdgcn_s_barrier(); \
    asm volatile("" ::: "memory"); \
    { const float* pr_ = pbuf + l15 * 68 + w * 16 + l4 * 4; \
      f32x4 s0 = *(const f32x4*)(pr_); \
      f32x4 s1 = *(const f32x4*)(pr_ + 1088); \
      f32x4 s2 = *(const f32x4*)(pr_ + 2176); \
      f32x4 s3 = *(const f32x4*)(pr_ + 3264); \
      f32x4 sm = (s0 + s1) + (s2 + s3); \
      u32x4 ow; \
      _Pragma("unroll") \
      for (int r = 0; r < 4; r++) { \
          float v = sm[r] + to_f32(PVUSE[r]); \
          v = v >= 0.f ? v : 0.01f * v; \
          ow[r] = ((unsigned)f2bf(v) << 16) | (tagS + 1u); \
      } \
      char* sp = hn32 + hrow * 4096 + col0 * 4; \
      asm volatile("global_store_dwordx4 %0, %1, off sc0 sc1" \
                   :: "v"(sp), "v"(ow) : "memory"); } \
    asm volatile("s_barrier" ::: "memory"); \
  } while (0)

template<typename PreT>
__global__ __launch_bounds__(256, 1)
void rnn_scan13(const unsigned short* __restrict__ WbotT,
                const PreT* __restrict__ pre,      // [T][B][H] t-major
                unsigned* __restrict__ hbuf32)     // [2][B][H] tagged u32
{
    using p4_t = typename pre4<PreT>::t;
    __shared__ unsigned short Ws[64 * 1024];      // 128KiB, XOR-swizzled rows
    __shared__ float pbuf[4 * 16 * 68];           // 17KB padded partial buffer
    const int tid = threadIdx.x, lane = tid & 63, w = tid >> 6;
    const int rg = (int)blockIdx.x >> 4;
    const int cs = (int)blockIdx.x & 15;
    const int row0 = rg * 16, n0 = cs * 64;

    // fill Ws swizzled: byte(r,kb) = r*2048 + (kb ^ ((r&7)<<4))
    for (int idx = tid; idx < 64 * 128; idx += 256) {
        int r = idx >> 7, kb = (idx & 127) * 16;
        s16x8 v = *(const s16x8*)(WbotT + (size_t)(n0 + r) * H_ + (idx & 127) * 8);
        *(s16x8*)((char*)Ws + r * 2048 + (kb ^ ((r & 7) << 4))) = v;
    }
    __syncthreads();

    const int l15 = lane & 15, l4 = lane >> 4;
    const int hrow = row0 + l15;              // h row this thread reads AND writes
    const int col0 = n0 + w * 16 + l4 * 4;    // 4 consecutive output cols (reduce phase)

    // swizzled Ws read bases: row = cg*16+l15, kbyte = l4*16 + (8w+j)*64
    const int b6 = (l15 >> 2) & 1;
    const char* wsRow = (const char*)Ws + l15 * 2048 + ((l4 * 16) ^ ((l15 & 3) << 4)) + w * 512;
    const char* wE = wsRow + b6 * 64;   // even j
    const char* wO = wsRow - b6 * 64;   // odd j

    int slp = 0;                        // adaptive pre-poll sleep (per wave)
    p4_t pvA, pvB;
    pvA = pre_ld(pre + (size_t)hrow * H_ + col0);   // pre[t=0]
    asm volatile("s_waitcnt vmcnt(0)" ::: "memory");

    for (int t = 0; t < T_; t += 2) {
        STEP(t,     pvA, pvB);
        STEP(t + 1, pvB, pvA);
    }
}

// ---------- launch ----------
extern "C" void kernel_launch(void* const* d_in, const int* in_sizes, int n_in,
                              void* d_out, int out_size, void* d_ws, size_t ws_size,
                              hipStream_t stream)
{
    const float* x     = (const float*)d_in[0];
    const float* W_in  = (const float*)d_in[1];
    const float* b_in  = (const float*)d_in[2];
    const float* W_h   = (const float*)d_in[3];
    const float* b_h   = (const float*)d_in[4];
    const float* W_out = (const float*)d_in[5];
    const float* b_out = (const float*)d_in[6];
    float* out = (float*)d_out;

    char* ws = (char*)d_ws;
    size_t off = 0;
    auto alloc = [&](size_t bytes) { void* p = ws + off; off += (bytes + 255) & ~(size_t)255; return p; };

    unsigned short* Xb    = (unsigned short*)alloc((size_t)MT_ * I_ * 2);
    unsigned short* WinT  = (unsigned short*)alloc((size_t)H_ * I_ * 2);
    unsigned short* WtopT = (unsigned short*)alloc((size_t)H_ * H_ * 2);
    unsigned short* WbotT = (unsigned short*)alloc((size_t)H_ * H_ * 2);
    unsigned short* WoutT = (unsigned short*)alloc((size_t)O_ * H_ * 2);
    unsigned short* Abuf  = (unsigned short*)alloc((size_t)MT_ * H_ * 2);
    unsigned*       hbuf32 = (unsigned*)alloc((size_t)2 * B_ * H_ * 4);   // tagged ping-pong
    unsigned short* hfin  = (unsigned short*)alloc((size_t)B_ * H_ * 2);  // stripped h_T
    void* pre = ws + off;
    const bool pre_f32 = (off + (size_t)MT_ * H_ * 4) <= ws_size;

    // memset 0: slot0 tag0 == step-0 tag (h0 = 0) ✓; slot1 tag0 != odd tags ✓
    hipMemsetAsync(hbuf32, 0, (size_t)2 * B_ * H_ * 4, stream);

    cvt_x<<<2048, 256, 0, stream>>>(x, Xb, MT_ * I_);
    dim3 tb(32, 8);
    cvt_t<<<dim3(H_ / 32, I_ / 32), tb, 0, stream>>>(W_in,  WinT,  I_, H_, 0);
    cvt_t<<<dim3(H_ / 32, H_ / 32), tb, 0, stream>>>(W_h,   WtopT, H_, H_, 0);
    cvt_t<<<dim3(H_ / 32, H_ / 32), tb, 0, stream>>>(W_h,   WbotT, H_, H_, H_);
    cvt_t<<<dim3(O_ / 32, H_ / 32), tb, 0, stream>>>(W_out, WoutT, H_, O_, 0);

    // GEMM1: A = lrelu(X @ W_in + b_in)   [MT, H] bf16
    gemm_bf16<unsigned short, true, false>
        <<<dim3(MT_ / 128, H_ / 128), 256, 0, stream>>>(Xb, WinT, b_in, Abuf, MT_, I_, H_);

    // GEMM2: pre = A @ Wtop + b_h   written t-major [T][B][H] with nt stores
    if (pre_f32) {
        gemm_bf16<float, false, true>
            <<<dim3(MT_ / 128, H_ / 128), 256, 0, stream>>>(Abuf, WtopT, b_h, (float*)pre, MT_, H_, H_);
        rnn_scan13<float><<<RG_ * CS_, 256, 0, stream>>>(WbotT, (const float*)pre, hbuf32);
    } else {
        gemm_bf16<unsigned short, false, true>
            <<<dim3(MT_ / 128, H_ / 128), 256, 0, stream>>>(Abuf, WtopT, b_h, (unsigned short*)pre, MT_, H_, H_);
        rnn_scan13<unsigned short><<<RG_ * CS_, 256, 0, stream>>>(WbotT, (const unsigned short*)pre, hbuf32);
    }

    // h_T lives in slot 0 (tag 1024); strip tags then final GEMM
    strip_h<<<64, 256, 0, stream>>>(hbuf32, hfin);
    gemm_bf16<float, false, false>
        <<<dim3(1, O_ / 128), 256, 0, stream>>>(hfin, WoutT, b_out, out, B_, H_, O_);
}

// Round 14
// 2952.792 us; speedup vs baseline: 2.4840x; 1.4926x over previous
//
#include <hip/hip_runtime.h>
#include <hip/hip_bf16.h>

// ---------- types ----------
typedef __attribute__((ext_vector_type(8))) short  s16x8;
typedef __attribute__((ext_vector_type(4))) float  f32x4;
typedef __attribute__((ext_vector_type(4))) unsigned short u16x4;
typedef __attribute__((ext_vector_type(4))) unsigned int   u32x4;

#define B_  64
#define T_  1024
#define I_  512
#define H_  1024
#define O_  512
#define MT_ 65536   // B_*T_

// scan decomposition: 4 row-groups x 16 col-slices; 4 waves split K
#define RG_   4
#define CS_   16

// ---------- helpers ----------
__device__ __forceinline__ unsigned short f2bf(float f) {
    unsigned u = __builtin_bit_cast(unsigned, f);
    u += 0x7FFFu + ((u >> 16) & 1u);
    return (unsigned short)(u >> 16);
}
__device__ __forceinline__ float bf2f(unsigned short h) {
    return __builtin_bit_cast(float, ((unsigned)h) << 16);
}
__device__ __forceinline__ void store_out(float* p, float v) { *p = v; }
__device__ __forceinline__ void store_out(unsigned short* p, float v) { *p = f2bf(v); }
// non-temporal stores for the streamed pre buffer
__device__ __forceinline__ void store_nt(float* p, float v) {
    asm volatile("global_store_dword %0, %1, off nt" :: "v"(p), "v"(v) : "memory");
}
__device__ __forceinline__ void store_nt(unsigned short* p, float v) {
    unsigned short h = f2bf(v);
    asm volatile("global_store_short %0, %1, off nt" :: "v"(p), "v"(h) : "memory");
}
__device__ __forceinline__ float to_f32(float v) { return v; }
__device__ __forceinline__ float to_f32(unsigned short v) { return bf2f(v); }

template<typename T> struct pre4;
template<> struct pre4<float>          { using t = f32x4; };
template<> struct pre4<unsigned short> { using t = u16x4; };

__device__ __forceinline__ f32x4 pre_ld(const float* p) {
    f32x4 d; asm volatile("global_load_dwordx4 %0, %1, off nt" : "=v"(d) : "v"(p)); return d;
}
__device__ __forceinline__ u16x4 pre_ld(const unsigned short* p) {
    u16x4 d; asm volatile("global_load_dwordx2 %0, %1, off nt" : "=v"(d) : "v"(p)); return d;
}

#define GL2LDS16(gp, lp) __builtin_amdgcn_global_load_lds( \
    (const __attribute__((address_space(1))) void*)(gp),   \
    (__attribute__((address_space(3))) void*)(lp), 16, 0, 0)

// ---------- conversion kernels ----------
__global__ void cvt_x(const float* __restrict__ src, unsigned short* __restrict__ dst, int n) {
    int stride = gridDim.x * blockDim.x * 4;
    for (int i = (blockIdx.x * blockDim.x + threadIdx.x) * 4; i < n; i += stride) {
        const float4 v = *(const float4*)(src + i);
        u16x4 o;
        o.x = f2bf(v.x); o.y = f2bf(v.y); o.z = f2bf(v.z); o.w = f2bf(v.w);
        *(u16x4*)(dst + i) = o;
    }
}

// dst[c][r] = bf16(src[row_off + r][c]);  src region [SR,SC] row-major -> dst [SC,SR]
__global__ void cvt_t(const float* __restrict__ src, unsigned short* __restrict__ dst,
                      int SR, int SC, int row_off) {
    __shared__ unsigned short tile[32][33];
    int c0 = blockIdx.x * 32, r0 = blockIdx.y * 32;
    int tx = threadIdx.x, ty = threadIdx.y;
    #pragma unroll
    for (int i = 0; i < 32; i += 8)
        tile[ty + i][tx] = f2bf(src[(size_t)(row_off + r0 + ty + i) * SC + c0 + tx]);
    __syncthreads();
    #pragma unroll
    for (int i = 0; i < 32; i += 8)
        dst[(size_t)(c0 + ty + i) * SR + r0 + tx] = tile[tx][ty + i];
}

// unscramble exchange layout (slot 0) -> row-major bf16 h_T.
// chunk idx: rg=idx>>12, q=(idx>>10)&3, i=(idx>>6)&15, lane=idx&63.
// element e: row = rg*16 + (lane&15), col = q*256 + (i>>1)*32 + (lane>>4)*8 + (i&1)*4 + e.
__global__ void strip_h(const unsigned* __restrict__ src, unsigned short* __restrict__ dst) {
    int idx = blockIdx.x * blockDim.x + threadIdx.x;   // 16384 chunks
    const unsigned* p = src + idx * 4;
    u32x4 v;
    asm volatile("global_load_dwordx4 %0, %1, off sc0 sc1" : "=v"(v) : "v"(p) : "memory");
    asm volatile("s_waitcnt vmcnt(0)" ::: "memory");
    int rg = idx >> 12, q = (idx >> 10) & 3, i = (idx >> 6) & 15, lane = idx & 63;
    int row = rg * 16 + (lane & 15);
    int col = q * 256 + (i >> 1) * 32 + (lane >> 4) * 8 + (i & 1) * 4;
    u16x4 o;
    o.x = (unsigned short)(v.x >> 16); o.y = (unsigned short)(v.y >> 16);
    o.z = (unsigned short)(v.z >> 16); o.w = (unsigned short)(v.w >> 16);
    *(u16x4*)(dst + (size_t)row * H_ + col) = o;
}

// ---------- generic bf16 MFMA GEMM: C[M,N] = act(A[M,K] @ BT[N,K]^T + bias) ----------
template<typename OutT, bool LRELU, bool SCATTER>
__global__ __launch_bounds__(256)
void gemm_bf16(const unsigned short* __restrict__ A,
               const unsigned short* __restrict__ BT,
               const float* __restrict__ bias,
               OutT* __restrict__ C, int M, int K, int N)
{
    __shared__ unsigned short As[4096]; // [128][32]
    __shared__ unsigned short Bs[4096]; // [128][32]
    const int tid = threadIdx.x, lane = tid & 63, wid = tid >> 6;
    const int wr = wid >> 1, wc = wid & 1;
    const int m0 = blockIdx.x * 128, n0 = blockIdx.y * 128;

    f32x4 acc[4][4] = {};

    const int c = wid * 2;
    const int srow = lane >> 2;
    const int scol = (lane & 3) * 8;
    const unsigned short* Ag0 = A  + (size_t)(m0 + c * 16 + srow) * K + scol;
    const unsigned short* Ag1 = A  + (size_t)(m0 + c * 16 + 16 + srow) * K + scol;
    const unsigned short* Bg0 = BT + (size_t)(n0 + c * 16 + srow) * K + scol;
    const unsigned short* Bg1 = BT + (size_t)(n0 + c * 16 + 16 + srow) * K + scol;

    for (int k0 = 0; k0 < K; k0 += 32) {
        __syncthreads();
        GL2LDS16(Ag0 + k0, As + c * 512);
        GL2LDS16(Ag1 + k0, As + (c + 1) * 512);
        GL2LDS16(Bg0 + k0, Bs + c * 512);
        GL2LDS16(Bg1 + k0, Bs + (c + 1) * 512);
        __syncthreads();

        s16x8 af[4], bfr[4];
        #pragma unroll
        for (int i = 0; i < 4; i++)
            af[i] = *(const s16x8*)(As + (wr * 64 + i * 16 + (lane & 15)) * 32 + (lane >> 4) * 8);
        #pragma unroll
        for (int j = 0; j < 4; j++)
            bfr[j] = *(const s16x8*)(Bs + (wc * 64 + j * 16 + (lane & 15)) * 32 + (lane >> 4) * 8);
        #pragma unroll
        for (int i = 0; i < 4; i++)
            #pragma unroll
            for (int j = 0; j < 4; j++)
                acc[i][j] = __builtin_amdgcn_mfma_f32_16x16x32_bf16(af[i], bfr[j], acc[i][j], 0, 0, 0);
    }

    #pragma unroll
    for (int j = 0; j < 4; j++) {
        const int n = n0 + wc * 64 + j * 16 + (lane & 15);
        const float bv = bias[n];
        #pragma unroll
        for (int i = 0; i < 4; i++) {
            #pragma unroll
            for (int r = 0; r < 4; r++) {
                const int m = m0 + wr * 64 + i * 16 + (lane >> 4) * 4 + r;
                if (m < M) {
                    float v = acc[i][j][r] + bv;
                    if (LRELU) v = v >= 0.f ? v : 0.01f * v;
                    if (SCATTER) {
                        size_t row = (size_t)((m & (T_ - 1)) * B_ + (m >> 10));
                        store_nt(&C[row * N + n], v);
                    } else {
                        store_out(&C[(size_t)m * N + n], v);
                    }
                }
            }
        }
    }
}

// ---------- scan v14: coalesced exchange layout ----------
// r13 protocol (tagged u32 ping-pong, adaptive sleep, nt pre) with the exchange
// buffer TRANSPOSED to wave geometry:
//   byte(rg,q,i,lane) = rg*65536 + q*16384 + i*1024 + lane*16
// where element (row=rg*16+(lane&15), col=q*256+(i>>1)*32+(lane>>4)*8+(i&1)*4+e).
// Consumer wave q: 16 polls of CONTIGUOUS 1KB (addr=base+lane*16, off=i*1024)
// -> 8x128B full-line transactions each, no duplicate line fetches (~2x fewer
// bytes+transactions than r13's fragmented pattern). Producer wave: 2x512B
// contiguous runs. Fragment->MFMA assembly identical to r13.

#define TAGLD(d, BASE, OFFSTR) asm volatile( \
    "global_load_dwordx4 %0, %1, off offset:" OFFSTR " sc0 sc1" \
    : "=v"(d) : "v"(BASE))

#define POLL16 do { \
    TAGLD(tv[0],  tA, "0");    TAGLD(tv[1],  tA, "1024"); \
    TAGLD(tv[2],  tA, "2048"); TAGLD(tv[3],  tA, "3072"); \
    TAGLD(tv[4],  tB, "0");    TAGLD(tv[5],  tB, "1024"); \
    TAGLD(tv[6],  tB, "2048"); TAGLD(tv[7],  tB, "3072"); \
    TAGLD(tv[8],  tC, "0");    TAGLD(tv[9],  tC, "1024"); \
    TAGLD(tv[10], tC, "2048"); TAGLD(tv[11], tC, "3072"); \
    TAGLD(tv[12], tD, "0");    TAGLD(tv[13], tD, "1024"); \
    TAGLD(tv[14], tD, "2048"); TAGLD(tv[15], tD, "3072"); \
    } while (0)

#define STEP(S, PVUSE, PVFILL) do { \
    const char* hc32 = (const char*)hbuf32 + (((S) & 1) << 18); \
    char*       hn32 = (char*)hbuf32 + ((((S) + 1) & 1) << 18); \
    const unsigned tagS = (unsigned)(S); \
    const char* tA = hc32 + tb_off; \
    const char* tB = tA + 4096; \
    const char* tC = tA + 8192; \
    const char* tD = tA + 12288; \
    for (int i_ = 0; i_ < slp; ++i_) __builtin_amdgcn_s_sleep(2); \
    u32x4 tv[16]; \
    unsigned ok = 0u; \
    int rounds_ = 0; \
    for (;;) { \
        if (!ok) { \
            POLL16; \
            asm volatile("s_waitcnt vmcnt(0)" ::: "memory"); \
            __builtin_amdgcn_sched_barrier(0); \
            unsigned d_ = 0; \
            _Pragma("unroll") \
            for (int i = 0; i < 16; i++) \
                d_ |= (tv[i].x ^ tagS) | (tv[i].y ^ tagS) | (tv[i].z ^ tagS) | (tv[i].w ^ tagS); \
            ok = ((d_ & 0xFFFFu) == 0u) ? 1u : 0u; \
        } \
        ++rounds_; \
        if (__all((int)ok)) break; \
    } \
    slp = (rounds_ > 1) ? (slp + 4 > 24 ? 24 : slp + 4) : (slp > 0 ? slp - 1 : 0); \
    { const int sn = ((S) + 1 < T_) ? (S) + 1 : (S); \
      PVFILL = pre_ld(pre + ((size_t)sn * B_ + hrow) * H_ + col0); } \
    f32x4 ac[4] = {}; \
    _Pragma("unroll") \
    for (int cg = 0; cg < 4; ++cg) { \
        const char* pE = wE + cg * 32768; \
        const char* pO = wO + cg * 32768; \
        _Pragma("unroll") \
        for (int j = 0; j < 8; ++j) { \
            u32x4 a_ = tv[2 * j], b_ = tv[2 * j + 1]; \
            u32x4 f_; \
            f_.x = (a_.x >> 16) | (a_.y & 0xFFFF0000u); \
            f_.y = (a_.z >> 16) | (a_.w & 0xFFFF0000u); \
            f_.z = (b_.x >> 16) | (b_.y & 0xFFFF0000u); \
            f_.w = (b_.z >> 16) | (b_.w & 0xFFFF0000u); \
            s16x8 hfrag = __builtin_bit_cast(s16x8, f_); \
            s16x8 g = *(const s16x8*)(((j & 1) ? pO : pE) + j * 64); \
            ac[cg] = __builtin_amdgcn_mfma_f32_16x16x32_bf16(g, hfrag, ac[cg], 0, 0, 0); \
        } \
    } \
    { float* pw_ = pbuf + (w * 16 + l15) * 68 + l4 * 4; \
      *(f32x4*)(pw_ +  0) = ac[0]; \
      *(f32x4*)(pw_ + 16) = ac[1]; \
      *(f32x4*)(pw_ + 32) = ac[2]; \
      *(f32x4*)(pw_ + 48) = ac[3]; } \
    asm volatile("s_waitcnt lgkmcnt(0)" ::: "memory"); \
    __builtin_amdgcn_s_barrier(); \
    asm volatile("" ::: "memory"); \
    { const float* pr_ = pbuf + l15 * 68 + w * 16 + l4 * 4; \
      f32x4 s0 = *(const f32x4*)(pr_); \
      f32x4 s1 = *(const f32x4*)(pr_ + 1088); \
      f32x4 s2 = *(const f32x4*)(pr_ + 2176); \
      f32x4 s3 = *(const f32x4*)(pr_ + 3264); \
      f32x4 sm = (s0 + s1) + (s2 + s3); \
      u32x4 ow; \
      _Pragma("unroll") \
      for (int r = 0; r < 4; r++) { \
          float v = sm[r] + to_f32(PVUSE[r]); \
          v = v >= 0.f ? v : 0.01f * v; \
          ow[r] = ((unsigned)f2bf(v) << 16) | (tagS + 1u); \
      } \
      char* sp = hn32 + sp_off; \
      asm volatile("global_store_dwordx4 %0, %1, off sc0 sc1" \
                   :: "v"(sp), "v"(ow) : "memory"); } \
    asm volatile("s_barrier" ::: "memory"); \
  } while (0)

template<typename PreT>
__global__ __launch_bounds__(256, 1)
void rnn_scan14(const unsigned short* __restrict__ WbotT,
                const PreT* __restrict__ pre,      // [T][B][H] t-major
                unsigned* __restrict__ hbuf32)     // [2][coalesced-layout] tagged u32
{
    using p4_t = typename pre4<PreT>::t;
    __shared__ unsigned short Ws[64 * 1024];      // 128KiB, XOR-swizzled rows
    __shared__ float pbuf[4 * 16 * 68];           // 17KB padded partial buffer
    const int tid = threadIdx.x, lane = tid & 63, w = tid >> 6;
    const int rg = (int)blockIdx.x >> 4;
    const int cs = (int)blockIdx.x & 15;
    const int row0 = rg * 16, n0 = cs * 64;

    // fill Ws swizzled: byte(r,kb) = r*2048 + (kb ^ ((r&7)<<4))
    for (int idx = tid; idx < 64 * 128; idx += 256) {
        int r = idx >> 7, kb = (idx & 127) * 16;
        s16x8 v = *(const s16x8*)(WbotT + (size_t)(n0 + r) * H_ + (idx & 127) * 8);
        *(s16x8*)((char*)Ws + r * 2048 + (kb ^ ((r & 7) << 4))) = v;
    }
    __syncthreads();

    const int l15 = lane & 15, l4 = lane >> 4;
    const int hrow = row0 + l15;              // h row this thread reads AND writes
    const int col0 = n0 + w * 16 + l4 * 4;    // 4 consecutive output cols

    // consumer poll base: wave w reads quarter q=w of its rg stripe
    const int tb_off = rg * 65536 + w * 16384 + lane * 16;
    // producer store offset: col0 -> (q, j, a, p), slot (a*16 + l15)
    const int q_ = col0 >> 8, jj_ = (col0 >> 5) & 7, aa_ = (col0 >> 3) & 3, pp_ = (col0 >> 2) & 1;
    const int sp_off = rg * 65536 + q_ * 16384 + (jj_ * 2 + pp_) * 1024 + (aa_ * 16 + l15) * 16;

    // swizzled Ws read bases: row = cg*16+l15, kbyte = l4*16 + (8w+j)*64
    const int b6 = (l15 >> 2) & 1;
    const char* wsRow = (const char*)Ws + l15 * 2048 + ((l4 * 16) ^ ((l15 & 3) << 4)) + w * 512;
    const char* wE = wsRow + b6 * 64;   // even j
    const char* wO = wsRow - b6 * 64;   // odd j

    int slp = 0;                        // adaptive pre-poll sleep (per wave)
    p4_t pvA, pvB;
    pvA = pre_ld(pre + (size_t)hrow * H_ + col0);   // pre[t=0]
    asm volatile("s_waitcnt vmcnt(0)" ::: "memory");

    for (int t = 0; t < T_; t += 2) {
        STEP(t,     pvA, pvB);
        STEP(t + 1, pvB, pvA);
    }
}

// ---------- launch ----------
extern "C" void kernel_launch(void* const* d_in, const int* in_sizes, int n_in,
                              void* d_out, int out_size, void* d_ws, size_t ws_size,
                              hipStream_t stream)
{
    const float* x     = (const float*)d_in[0];
    const float* W_in  = (const float*)d_in[1];
    const float* b_in  = (const float*)d_in[2];
    const float* W_h   = (const float*)d_in[3];
    const float* b_h   = (const float*)d_in[4];
    const float* W_out = (const float*)d_in[5];
    const float* b_out = (const float*)d_in[6];
    float* out = (float*)d_out;

    char* ws = (char*)d_ws;
    size_t off = 0;
    auto alloc = [&](size_t bytes) { void* p = ws + off; off += (bytes + 255) & ~(size_t)255; return p; };

    unsigned short* Xb    = (unsigned short*)alloc((size_t)MT_ * I_ * 2);
    unsigned short* WinT  = (unsigned short*)alloc((size_t)H_ * I_ * 2);
    unsigned short* WtopT = (unsigned short*)alloc((size_t)H_ * H_ * 2);
    unsigned short* WbotT = (unsigned short*)alloc((size_t)H_ * H_ * 2);
    unsigned short* WoutT = (unsigned short*)alloc((size_t)O_ * H_ * 2);
    unsigned short* Abuf  = (unsigned short*)alloc((size_t)MT_ * H_ * 2);
    unsigned*       hbuf32 = (unsigned*)alloc((size_t)2 * B_ * H_ * 4);   // tagged ping-pong
    unsigned short* hfin  = (unsigned short*)alloc((size_t)B_ * H_ * 2);  // unscrambled h_T
    void* pre = ws + off;
    const bool pre_f32 = (off + (size_t)MT_ * H_ * 4) <= ws_size;

    // memset 0: slot0 tag0 == step-0 tag (h0 = 0, any layout) ✓; slot1 tag0 != odd tags ✓
    hipMemsetAsync(hbuf32, 0, (size_t)2 * B_ * H_ * 4, stream);

    cvt_x<<<2048, 256, 0, stream>>>(x, Xb, MT_ * I_);
    dim3 tb(32, 8);
    cvt_t<<<dim3(H_ / 32, I_ / 32), tb, 0, stream>>>(W_in,  WinT,  I_, H_, 0);
    cvt_t<<<dim3(H_ / 32, H_ / 32), tb, 0, stream>>>(W_h,   WtopT, H_, H_, 0);
    cvt_t<<<dim3(H_ / 32, H_ / 32), tb, 0, stream>>>(W_h,   WbotT, H_, H_, H_);
    cvt_t<<<dim3(O_ / 32, H_ / 32), tb, 0, stream>>>(W_out, WoutT, H_, O_, 0);

    // GEMM1: A = lrelu(X @ W_in + b_in)   [MT, H] bf16
    gemm_bf16<unsigned short, true, false>
        <<<dim3(MT_ / 128, H_ / 128), 256, 0, stream>>>(Xb, WinT, b_in, Abuf, MT_, I_, H_);

    // GEMM2: pre = A @ Wtop + b_h   written t-major [T][B][H] with nt stores
    if (pre_f32) {
        gemm_bf16<float, false, true>
            <<<dim3(MT_ / 128, H_ / 128), 256, 0, stream>>>(Abuf, WtopT, b_h, (float*)pre, MT_, H_, H_);
        rnn_scan14<float><<<RG_ * CS_, 256, 0, stream>>>(WbotT, (const float*)pre, hbuf32);
    } else {
        gemm_bf16<unsigned short, false, true>
            <<<dim3(MT_ / 128, H_ / 128), 256, 0, stream>>>(Abuf, WtopT, b_h, (unsigned short*)pre, MT_, H_, H_);
        rnn_scan14<unsigned short><<<RG_ * CS_, 256, 0, stream>>>(WbotT, (const unsigned short*)pre, hbuf32);
    }

    // h_T in slot 0 (tag 1024, coalesced layout); unscramble then final GEMM
    strip_h<<<64, 256, 0, stream>>>(hbuf32, hfin);
    gemm_bf16<float, false, false>
        <<<dim3(1, O_ / 128), 256, 0, stream>>>(hfin, WoutT, b_out, out, B_, H_, O_);
}

// Round 15
// 2882.075 us; speedup vs baseline: 2.5449x; 1.0245x over previous
//
#include <hip/hip_runtime.h>
#include <hip/hip_bf16.h>

// ---------- types ----------
typedef __attribute__((ext_vector_type(8))) short  s16x8;
typedef __attribute__((ext_vector_type(4))) float  f32x4;
typedef __attribute__((ext_vector_type(4))) unsigned short u16x4;
typedef __attribute__((ext_vector_type(4))) unsigned int   u32x4;

#define B_  64
#define T_  1024
#define I_  512
#define H_  1024
#define O_  512
#define MT_ 65536   // B_*T_

// scan decomposition: 8 row-groups (8 rows, rg = blockIdx&7 -> one XCD under
// round-robin dispatch) x 16 col-slices; 4 waves split K. 128 blocks.
#define RG_   8
#define CS_   16

// ---------- helpers ----------
__device__ __forceinline__ unsigned short f2bf(float f) {
    unsigned u = __builtin_bit_cast(unsigned, f);
    u += 0x7FFFu + ((u >> 16) & 1u);
    return (unsigned short)(u >> 16);
}
__device__ __forceinline__ float bf2f(unsigned short h) {
    return __builtin_bit_cast(float, ((unsigned)h) << 16);
}
__device__ __forceinline__ void store_out(float* p, float v) { *p = v; }
__device__ __forceinline__ void store_out(unsigned short* p, float v) { *p = f2bf(v); }
__device__ __forceinline__ void store_nt(float* p, float v) {
    asm volatile("global_store_dword %0, %1, off nt" :: "v"(p), "v"(v) : "memory");
}
__device__ __forceinline__ void store_nt(unsigned short* p, float v) {
    unsigned short h = f2bf(v);
    asm volatile("global_store_short %0, %1, off nt" :: "v"(p), "v"(h) : "memory");
}
__device__ __forceinline__ float to_f32(float v) { return v; }
__device__ __forceinline__ float to_f32(unsigned short v) { return bf2f(v); }

template<typename T> struct pre4;
template<> struct pre4<float>          { using t = f32x4; };
template<> struct pre4<unsigned short> { using t = u16x4; };

__device__ __forceinline__ f32x4 pre_ld(const float* p) {
    f32x4 d; asm volatile("global_load_dwordx4 %0, %1, off nt" : "=v"(d) : "v"(p)); return d;
}
__device__ __forceinline__ u16x4 pre_ld(const unsigned short* p) {
    u16x4 d; asm volatile("global_load_dwordx2 %0, %1, off nt" : "=v"(d) : "v"(p)); return d;
}

#define GL2LDS16(gp, lp) __builtin_amdgcn_global_load_lds( \
    (const __attribute__((address_space(1))) void*)(gp),   \
    (__attribute__((address_space(3))) void*)(lp), 16, 0, 0)

// ---------- conversion kernels ----------
__global__ void cvt_x(const float* __restrict__ src, unsigned short* __restrict__ dst, int n) {
    int stride = gridDim.x * blockDim.x * 4;
    for (int i = (blockIdx.x * blockDim.x + threadIdx.x) * 4; i < n; i += stride) {
        const float4 v = *(const float4*)(src + i);
        u16x4 o;
        o.x = f2bf(v.x); o.y = f2bf(v.y); o.z = f2bf(v.z); o.w = f2bf(v.w);
        *(u16x4*)(dst + i) = o;
    }
}

// dst[c][r] = bf16(src[row_off + r][c]);  src region [SR,SC] row-major -> dst [SC,SR]
__global__ void cvt_t(const float* __restrict__ src, unsigned short* __restrict__ dst,
                      int SR, int SC, int row_off) {
    __shared__ unsigned short tile[32][33];
    int c0 = blockIdx.x * 32, r0 = blockIdx.y * 32;
    int tx = threadIdx.x, ty = threadIdx.y;
    #pragma unroll
    for (int i = 0; i < 32; i += 8)
        tile[ty + i][tx] = f2bf(src[(size_t)(row_off + r0 + ty + i) * SC + c0 + tx]);
    __syncthreads();
    #pragma unroll
    for (int i = 0; i < 32; i += 8)
        dst[(size_t)(c0 + ty + i) * SR + r0 + tx] = tile[tx][ty + i];
}

// unscramble exchange layout (slot 0) -> row-major bf16 h_T.
// Plain loads: end-of-dispatch writeback makes the scan's dirty L2 lines visible.
__global__ void strip_h(const unsigned* __restrict__ src, unsigned short* __restrict__ dst) {
    int idx = blockIdx.x * blockDim.x + threadIdx.x;   // 16384 chunks
    u32x4 v = *(const u32x4*)(src + idx * 4);
    int rg = idx >> 11, c2 = idx & 2047;
    int q = c2 >> 9, c3 = c2 & 511;
    int j = c3 >> 6, c = c3 & 63;
    int p = c >> 5, a = (c >> 3) & 3, row = c & 7;
    int grow = rg * 8 + row;
    int col = q * 256 + j * 32 + a * 8 + p * 4;
    u16x4 o;
    o.x = (unsigned short)(v.x >> 16); o.y = (unsigned short)(v.y >> 16);
    o.z = (unsigned short)(v.z >> 16); o.w = (unsigned short)(v.w >> 16);
    *(u16x4*)(dst + (size_t)grow * H_ + col) = o;
}

// ---------- generic bf16 MFMA GEMM: C[M,N] = act(A[M,K] @ BT[N,K]^T + bias) ----------
template<typename OutT, bool LRELU, bool SCATTER>
__global__ __launch_bounds__(256)
void gemm_bf16(const unsigned short* __restrict__ A,
               const unsigned short* __restrict__ BT,
               const float* __restrict__ bias,
               OutT* __restrict__ C, int M, int K, int N)
{
    __shared__ unsigned short As[4096]; // [128][32]
    __shared__ unsigned short Bs[4096]; // [128][32]
    const int tid = threadIdx.x, lane = tid & 63, wid = tid >> 6;
    const int wr = wid >> 1, wc = wid & 1;
    const int m0 = blockIdx.x * 128, n0 = blockIdx.y * 128;

    f32x4 acc[4][4] = {};

    const int c = wid * 2;
    const int srow = lane >> 2;
    const int scol = (lane & 3) * 8;
    const unsigned short* Ag0 = A  + (size_t)(m0 + c * 16 + srow) * K + scol;
    const unsigned short* Ag1 = A  + (size_t)(m0 + c * 16 + 16 + srow) * K + scol;
    const unsigned short* Bg0 = BT + (size_t)(n0 + c * 16 + srow) * K + scol;
    const unsigned short* Bg1 = BT + (size_t)(n0 + c * 16 + 16 + srow) * K + scol;

    for (int k0 = 0; k0 < K; k0 += 32) {
        __syncthreads();
        GL2LDS16(Ag0 + k0, As + c * 512);
        GL2LDS16(Ag1 + k0, As + (c + 1) * 512);
        GL2LDS16(Bg0 + k0, Bs + c * 512);
        GL2LDS16(Bg1 + k0, Bs + (c + 1) * 512);
        __syncthreads();

        s16x8 af[4], bfr[4];
        #pragma unroll
        for (int i = 0; i < 4; i++)
            af[i] = *(const s16x8*)(As + (wr * 64 + i * 16 + (lane & 15)) * 32 + (lane >> 4) * 8);
        #pragma unroll
        for (int j = 0; j < 4; j++)
            bfr[j] = *(const s16x8*)(Bs + (wc * 64 + j * 16 + (lane & 15)) * 32 + (lane >> 4) * 8);
        #pragma unroll
        for (int i = 0; i < 4; i++)
            #pragma unroll
            for (int j = 0; j < 4; j++)
                acc[i][j] = __builtin_amdgcn_mfma_f32_16x16x32_bf16(af[i], bfr[j], acc[i][j], 0, 0, 0);
    }

    #pragma unroll
    for (int j = 0; j < 4; j++) {
        const int n = n0 + wc * 64 + j * 16 + (lane & 15);
        const float bv = bias[n];
        #pragma unroll
        for (int i = 0; i < 4; i++) {
            #pragma unroll
            for (int r = 0; r < 4; r++) {
                const int m = m0 + wr * 64 + i * 16 + (lane >> 4) * 4 + r;
                if (m < M) {
                    float v = acc[i][j][r] + bv;
                    if (LRELU) v = v >= 0.f ? v : 0.01f * v;
                    if (SCATTER) {
                        size_t row = (size_t)((m & (T_ - 1)) * B_ + (m >> 10));
                        store_nt(&C[row * N + n], v);
                    } else {
                        store_out(&C[(size_t)m * N + n], v);
                    }
                }
            }
        }
    }
}

// ---------- scan v15: XCD-local sc0 exchange + deadlock-proof distress fallback ----
// 128 blocks (8 rg x 16 cs). Tagged u32 ping-pong (r14 protocol) but stores/polls
// are sc0 ONLY: co-located producer stores UPDATE the shared L2 line in place;
// polls are L2 hits. Safety: if ANY cross-XCD pair exists, the whole rg stalls
// within one step (full coupling) -> stuck waves check/raise a global distress
// flag every 16 poll rounds, re-publish their last output sc1, and permanently
// switch to the proven sc1 (L3) protocol. Bounded worst case = r14 + ~30us.
// Exchange layout (stripe 32KB/rg): byte = rg*32768 + q*8192 + j*1024 + p*512
// + (a*8+row)*16, value = h[rg*8+row][q*256 + j*32 + a*8 + p*4 + e].

#define TAGLD2(d, BASE, OFFSTR, SC) asm volatile( \
    "global_load_dwordx4 %0, %1, off offset:" OFFSTR " " SC \
    : "=v"(d) : "v"(BASE))

#define POLLBODY(SC) do { \
    TAGLD2(tv[0],  tA, "0",   SC); TAGLD2(tv[1],  tA, "512",  SC); \
    TAGLD2(tv[2],  tA, "1024",SC); TAGLD2(tv[3],  tA, "1536", SC); \
    TAGLD2(tv[4],  tA, "2048",SC); TAGLD2(tv[5],  tA, "2560", SC); \
    TAGLD2(tv[6],  tA, "3072",SC); TAGLD2(tv[7],  tA, "3584", SC); \
    TAGLD2(tv[8],  tB, "0",   SC); TAGLD2(tv[9],  tB, "512",  SC); \
    TAGLD2(tv[10], tB, "1024",SC); TAGLD2(tv[11], tB, "1536", SC); \
    TAGLD2(tv[12], tB, "2048",SC); TAGLD2(tv[13], tB, "2560", SC); \
    TAGLD2(tv[14], tB, "3072",SC); TAGLD2(tv[15], tB, "3584", SC); \
    } while (0)

#define STEP(S, PVUSE, PVFILL) do { \
    const char* hc32 = (const char*)hbuf32 + (((S) & 1) << 18); \
    char*       hn32 = (char*)hbuf32 + ((((S) + 1) & 1) << 18); \
    const unsigned tagS = (unsigned)(S); \
    const char* tA = hc32 + tbA_off; \
    const char* tB = tA + 4096; \
    for (int i_ = 0; i_ < slp; ++i_) __builtin_amdgcn_s_sleep(2); \
    u32x4 tv[16]; \
    unsigned ok = 0u; \
    int rounds_ = 0; \
    for (;;) { \
        if (!ok) { \
            if (!gmode) { POLLBODY("sc0"); } else { POLLBODY("sc0 sc1"); } \
            asm volatile("s_waitcnt vmcnt(0)" ::: "memory"); \
            __builtin_amdgcn_sched_barrier(0); \
            unsigned d_ = 0; \
            _Pragma("unroll") \
            for (int i = 0; i < 16; i++) \
                d_ |= (tv[i].x ^ tagS) | (tv[i].y ^ tagS) | (tv[i].z ^ tagS) | (tv[i].w ^ tagS); \
            ok = ((d_ & 0xFFFFu) == 0u) ? 1u : 0u; \
        } \
        ++rounds_; \
        if (__all((int)ok)) break; \
        if ((rounds_ & 15) == 0) { \
            unsigned fl; \
            asm volatile("global_load_dword %0, %1, off sc0 sc1\n\t" \
                         "s_waitcnt vmcnt(0)" : "=v"(fl) : "v"(dflag) : "memory"); \
            bool anyfl = __any((int)(fl != 0u)); \
            if (!gmode && (anyfl || rounds_ > 96)) { \
                if (!anyfl && lane == 0) { \
                    unsigned one_ = 1u; \
                    asm volatile("global_store_dword %0, %1, off sc0 sc1" \
                                 :: "v"(dflag), "v"(one_) : "memory"); \
                } \
                gmode = 1u; \
                asm volatile("global_store_dwordx4 %0, %1, off sc0 sc1" \
                             :: "v"(lastsp), "v"(lastow) : "memory"); \
            } \
        } \
        __builtin_amdgcn_s_sleep(1); \
    } \
    slp = (rounds_ > 1) ? (slp + 4 > 24 ? 24 : slp + 4) : (slp > 0 ? slp - 1 : 0); \
    { const int sn = ((S) + 1 < T_) ? (S) + 1 : (S); \
      PVFILL = pre_ld(pre + ((size_t)sn * B_ + hrow) * H_ + col0); } \
    f32x4 ac[4] = {}; \
    _Pragma("unroll") \
    for (int cg = 0; cg < 4; ++cg) { \
        const char* pE = wE + cg * 32768; \
        const char* pO = wO + cg * 32768; \
        _Pragma("unroll") \
        for (int j = 0; j < 8; ++j) { \
            u32x4 a2_ = tv[2 * j], b2_ = tv[2 * j + 1]; \
            u32x4 f_; \
            f_.x = (a2_.x >> 16) | (a2_.y & 0xFFFF0000u); \
            f_.y = (a2_.z >> 16) | (a2_.w & 0xFFFF0000u); \
            f_.z = (b2_.x >> 16) | (b2_.y & 0xFFFF0000u); \
            f_.w = (b2_.z >> 16) | (b2_.w & 0xFFFF0000u); \
            s16x8 hfrag = __builtin_bit_cast(s16x8, f_); \
            s16x8 g = *(const s16x8*)(((j & 1) ? pO : pE) + j * 64); \
            ac[cg] = __builtin_amdgcn_mfma_f32_16x16x32_bf16(g, hfrag, ac[cg], 0, 0, 0); \
        } \
    } \
    if (l15 < 8) { \
        float* pw_ = pbuf + (w * 8 + l15) * 68 + l4 * 4; \
        *(f32x4*)(pw_ +  0) = ac[0]; \
        *(f32x4*)(pw_ + 16) = ac[1]; \
        *(f32x4*)(pw_ + 32) = ac[2]; \
        *(f32x4*)(pw_ + 48) = ac[3]; \
    } \
    asm volatile("s_waitcnt lgkmcnt(0)" ::: "memory"); \
    __builtin_amdgcn_s_barrier(); \
    asm volatile("" ::: "memory"); \
    if (l15 < 8) { \
        const float* pr_ = pbuf + l15 * 68 + w * 16 + l4 * 4; \
        f32x4 s0 = *(const f32x4*)(pr_); \
        f32x4 s1 = *(const f32x4*)(pr_ + 544); \
        f32x4 s2 = *(const f32x4*)(pr_ + 1088); \
        f32x4 s3 = *(const f32x4*)(pr_ + 1632); \
        f32x4 sm = (s0 + s1) + (s2 + s3); \
        u32x4 ow; \
        _Pragma("unroll") \
        for (int r = 0; r < 4; r++) { \
            float v = sm[r] + to_f32(PVUSE[r]); \
            v = v >= 0.f ? v : 0.01f * v; \
            ow[r] = ((unsigned)f2bf(v) << 16) | (tagS + 1u); \
        } \
        char* sp = hn32 + sp_off; \
        if (!gmode) { \
            asm volatile("global_store_dwordx4 %0, %1, off sc0" \
                         :: "v"(sp), "v"(ow) : "memory"); \
        } else { \
            asm volatile("global_store_dwordx4 %0, %1, off sc0 sc1" \
                         :: "v"(sp), "v"(ow) : "memory"); \
        } \
        lastow = ow; lastsp = sp; \
    } \
    asm volatile("s_barrier" ::: "memory"); \
  } while (0)

template<typename PreT>
__global__ __launch_bounds__(256, 1)
void rnn_scan15(const unsigned short* __restrict__ WbotT,
                const PreT* __restrict__ pre,      // [T][B][H] t-major
                unsigned* __restrict__ hbuf32,     // [2][exchange layout] tagged u32
                unsigned* __restrict__ dflag)      // distress flag + scratch
{
    using p4_t = typename pre4<PreT>::t;
    __shared__ unsigned short Ws[64 * 1024];      // 128KiB, XOR-swizzled rows
    __shared__ float pbuf[4 * 8 * 68];            // 8.7KB padded partial buffer
    const int tid = threadIdx.x, lane = tid & 63, w = tid >> 6;
    const int rg = (int)blockIdx.x & 7;           // &7 -> same rg = same XCD (round-robin)
    const int cs = (int)blockIdx.x >> 3;
    const int n0 = cs * 64;

    // fill Ws swizzled: byte(r,kb) = r*2048 + (kb ^ ((r&7)<<4))
    for (int idx = tid; idx < 64 * 128; idx += 256) {
        int r = idx >> 7, kb = (idx & 127) * 16;
        s16x8 v = *(const s16x8*)(WbotT + (size_t)(n0 + r) * H_ + (idx & 127) * 8);
        *(s16x8*)((char*)Ws + r * 2048 + (kb ^ ((r & 7) << 4))) = v;
    }
    __syncthreads();

    const int l15 = lane & 15, l4 = lane >> 4;
    const int hrow = rg * 8 + (l15 & 7);          // 8 rows; lanes l15>=8 duplicate
    const int col0 = n0 + w * 16 + l4 * 4;        // 4 consecutive output cols

    // consumer poll base (wave w = k-quarter q): lane -> (a=lane>>4, row=lane&7)
    const int tbA_off = rg * 32768 + w * 8192 + (lane >> 4) * 128 + (lane & 7) * 16;
    // producer store offset for (row=l15, col0..col0+3)
    const int q_ = col0 >> 8, j_ = (col0 >> 5) & 7, a_ = (col0 >> 3) & 3, p_ = (col0 >> 2) & 1;
    const int sp_off = rg * 32768 + q_ * 8192 + j_ * 1024 + p_ * 512 + (a_ * 8 + (l15 & 7)) * 16;

    // swizzled Ws read bases (unchanged from r14)
    const int b6 = (l15 >> 2) & 1;
    const char* wsRow = (const char*)Ws + l15 * 2048 + ((l4 * 16) ^ ((l15 & 3) << 4)) + w * 512;
    const char* wE = wsRow + b6 * 64;   // even j
    const char* wO = wsRow - b6 * 64;   // odd j

    int slp = 0;                        // adaptive pre-poll sleep (per wave)
    unsigned gmode = 0;                 // 0 = XCD-local sc0, 1 = L3 sc1 (sticky)
    u32x4 lastow = {};
    char* lastsp = (char*)dflag + 1024 + tid * 16;   // harmless scratch until first store

    p4_t pvA, pvB;
    pvA = pre_ld(pre + (size_t)hrow * H_ + col0);   // pre[t=0]
    asm volatile("s_waitcnt vmcnt(0)" ::: "memory");

    for (int t = 0; t < T_; t += 2) {
        STEP(t,     pvA, pvB);
        STEP(t + 1, pvB, pvA);
    }
}

// ---------- launch ----------
extern "C" void kernel_launch(void* const* d_in, const int* in_sizes, int n_in,
                              void* d_out, int out_size, void* d_ws, size_t ws_size,
                              hipStream_t stream)
{
    const float* x     = (const float*)d_in[0];
    const float* W_in  = (const float*)d_in[1];
    const float* b_in  = (const float*)d_in[2];
    const float* W_h   = (const float*)d_in[3];
    const float* b_h   = (const float*)d_in[4];
    const float* W_out = (const float*)d_in[5];
    const float* b_out = (const float*)d_in[6];
    float* out = (float*)d_out;

    char* ws = (char*)d_ws;
    size_t off = 0;
    auto alloc = [&](size_t bytes) { void* p = ws + off; off += (bytes + 255) & ~(size_t)255; return p; };

    unsigned short* Xb    = (unsigned short*)alloc((size_t)MT_ * I_ * 2);
    unsigned short* WinT  = (unsigned short*)alloc((size_t)H_ * I_ * 2);
    unsigned short* WtopT = (unsigned short*)alloc((size_t)H_ * H_ * 2);
    unsigned short* WbotT = (unsigned short*)alloc((size_t)H_ * H_ * 2);
    unsigned short* WoutT = (unsigned short*)alloc((size_t)O_ * H_ * 2);
    unsigned short* Abuf  = (unsigned short*)alloc((size_t)MT_ * H_ * 2);
    unsigned*       hbuf32 = (unsigned*)alloc((size_t)2 * B_ * H_ * 4);   // tagged ping-pong
    unsigned*       dbuf  = (unsigned*)alloc(8192);                       // distress + scratch
    unsigned short* hfin  = (unsigned short*)alloc((size_t)B_ * H_ * 2);  // unscrambled h_T
    void* pre = ws + off;
    const bool pre_f32 = (off + (size_t)MT_ * H_ * 4) <= ws_size;

    // memset 0: slot0 tag0 == step-0 tag (h0 = 0, any layout) ✓; slot1 tag0 != odd tags ✓
    hipMemsetAsync(hbuf32, 0, (size_t)2 * B_ * H_ * 4, stream);
    hipMemsetAsync(dbuf, 0, 8192, stream);

    cvt_x<<<2048, 256, 0, stream>>>(x, Xb, MT_ * I_);
    dim3 tb(32, 8);
    cvt_t<<<dim3(H_ / 32, I_ / 32), tb, 0, stream>>>(W_in,  WinT,  I_, H_, 0);
    cvt_t<<<dim3(H_ / 32, H_ / 32), tb, 0, stream>>>(W_h,   WtopT, H_, H_, 0);
    cvt_t<<<dim3(H_ / 32, H_ / 32), tb, 0, stream>>>(W_h,   WbotT, H_, H_, H_);
    cvt_t<<<dim3(O_ / 32, H_ / 32), tb, 0, stream>>>(W_out, WoutT, H_, O_, 0);

    // GEMM1: A = lrelu(X @ W_in + b_in)   [MT, H] bf16
    gemm_bf16<unsigned short, true, false>
        <<<dim3(MT_ / 128, H_ / 128), 256, 0, stream>>>(Xb, WinT, b_in, Abuf, MT_, I_, H_);

    // GEMM2: pre = A @ Wtop + b_h   written t-major [T][B][H] with nt stores
    if (pre_f32) {
        gemm_bf16<float, false, true>
            <<<dim3(MT_ / 128, H_ / 128), 256, 0, stream>>>(Abuf, WtopT, b_h, (float*)pre, MT_, H_, H_);
        rnn_scan15<float><<<RG_ * CS_, 256, 0, stream>>>(WbotT, (const float*)pre, hbuf32, dbuf);
    } else {
        gemm_bf16<unsigned short, false, true>
            <<<dim3(MT_ / 128, H_ / 128), 256, 0, stream>>>(Abuf, WtopT, b_h, (unsigned short*)pre, MT_, H_, H_);
        rnn_scan15<unsigned short><<<RG_ * CS_, 256, 0, stream>>>(WbotT, (const unsigned short*)pre, hbuf32, dbuf);
    }

    // h_T in slot 0 (tag 1024); unscramble (end-of-dispatch flush makes it coherent)
    strip_h<<<64, 256, 0, stream>>>(hbuf32, hfin);
    gemm_bf16<float, false, false>
        <<<dim3(1, O_ / 128), 256, 0, stream>>>(hfin, WoutT, b_out, out, B_, H_, O_);
}